// Round 25
// baseline (185.295 us; speedup 1.0000x reference)
//
#include <hip/hip_runtime.h>
#include <math.h>

#define Bsz 1024
#define Din 512
#define Hdim 1024
#define Aact 64
#define MAXT 23   // max row-tiles across experts: 7 partial + 16
#define NXCD 8

// out layout (float32): option_probs[1024*8] | action_probs[1024*64] | term[1024] | opt_argmax[1024] | sel_action[1024]
#define OFF_ACT   8192
#define OFF_TERM  73728
#define OFF_OARG  74752
#define OFF_SACT  75776

typedef __attribute__((ext_vector_type(8))) short bf16x8;
typedef __attribute__((ext_vector_type(4))) float f32x4;

// ---------------- threefry2x32-20, key (0,42), partitionable XOR-fold (verified R3-R24) ----------------
__device__ __forceinline__ unsigned rotl32(unsigned x, int d){ return (x << d) | (x >> (32 - d)); }

__device__ __forceinline__ void threefry_042(unsigned& x0, unsigned& x1){
  const unsigned ks0 = 0u, ks1 = 42u, ks2 = 0x1BD11BDAu ^ 0u ^ 42u;
  x0 += ks0; x1 += ks1;
#define TFR(r) { x0 += x1; x1 = rotl32(x1, r); x1 ^= x0; }
  TFR(13) TFR(15) TFR(26) TFR(6)  x0 += ks1; x1 += ks2 + 1u;
  TFR(17) TFR(29) TFR(16) TFR(24) x0 += ks2; x1 += ks0 + 2u;
  TFR(13) TFR(15) TFR(26) TFR(6)  x0 += ks0; x1 += ks1 + 3u;
  TFR(17) TFR(29) TFR(16) TFR(24) x0 += ks1; x1 += ks2 + 4u;
  TFR(13) TFR(15) TFR(26) TFR(6)  x0 += ks2; x1 += ks0 + 5u;
#undef TFR
}

__device__ __forceinline__ float gumbel_at(int idx){
  unsigned x0 = 0u, x1 = (unsigned)idx;
  threefry_042(x0, x1);
  unsigned bits = x0 ^ x1;
  float f = __uint_as_float((bits >> 9) | 0x3F800000u) - 1.0f;
  float u = fmaxf(f, 1.1754944e-38f);
  return -logf(-logf(u));
}

// ---------------- bf16 hi/lo split helpers (RNE) ----------------
__device__ __forceinline__ unsigned short bf16_rne(float x){
  unsigned u = __float_as_uint(x);
  return (unsigned short)((u + 0x7FFFu + ((u >> 16) & 1u)) >> 16);
}
__device__ __forceinline__ float bf16_tof(unsigned short h){
  return __uint_as_float(((unsigned)h) << 16);
}

// ---------------- state -> hi/lo bf16 (row-major, same indexing) ----------------
__global__ __launch_bounds__(256)
void convert_state(const float* __restrict__ st, unsigned short* __restrict__ hi,
                   unsigned short* __restrict__ lo)
{
  const int i = (blockIdx.x * 256 + threadIdx.x) * 4;
  float4 v = *(const float4*)(st + i);
  ushort4 h, l;
  h.x = bf16_rne(v.x); l.x = bf16_rne(v.x - bf16_tof(h.x));
  h.y = bf16_rne(v.y); l.y = bf16_rne(v.y - bf16_tof(h.y));
  h.z = bf16_rne(v.z); l.z = bf16_rne(v.z - bf16_tof(h.z));
  h.w = bf16_rne(v.w); l.w = bf16_rne(v.w - bf16_tof(h.w));
  *(ushort4*)(hi + i) = h;
  *(ushort4*)(lo + i) = l;
}

// ---------------- bf16x3 MFMA GEMM: 64x64 tile, 4 waves, k-step 64, T14 async-STAGE dbuf ----------
// R25 = R24 + T14 split: LOADR (global->regs) issued BEFORE compute, WRITE (convert+ds_write to
// buf^1) AFTER compute — the counted vmcnt wait lands after the MFMA burst, hiding HBM latency.
// (R24's stage-then-compute stalled at vmcnt before ever reaching the MFMAs — dbuf was a wash.)
// a*b ~= ahi*bhi + ahi*blo + alo*bhi (fp32 MFMA accum); error class == fp32 split-K reorder.
// mfma_f32_16x16x32_bf16 layouts: A row=l&15,k=(l>>4)*8+e; B col=l&15; D col=l&15,row=(l>>4)*4+r.
template<bool DENSE, bool GATHER, bool HILOOUT>
__global__ __launch_bounds__(256)
void mfma_gemm(const unsigned short* __restrict__ Ahi, const unsigned short* __restrict__ Alo,
               int lda,
               const float* __restrict__ W0, const float* __restrict__ W1, long long wstride,
               const float* __restrict__ b0, const float* __restrict__ b1, int bstride,
               float* __restrict__ C0, float* __restrict__ C1,
               unsigned short* __restrict__ Chi, unsigned short* __restrict__ Clo,
               int N, int K,
               const int* __restrict__ order, const int* __restrict__ offsets,
               const int* __restrict__ tlist)
{
  const float* W; const float* bias; float* C;
  int mbase, r1, n0;
  if (DENSE){
    const int bid = (int)(blockIdx.x + 16u*blockIdx.y + 256u*blockIdx.z);
    const int wf = (bid & 7) * 64 + (bid >> 3);     // bijective XCD swizzle
    const int ny = wf & 15, mx = (wf >> 4) & 15, z = wf >> 8;
    mbase = mx * 64; r1 = Bsz; n0 = ny * 64;
    W = z ? W1 : W0; bias = z ? b1 : b0; C = z ? C1 : C0;
  } else {
    const int bid = (int)(blockIdx.x + gridDim.x * blockIdx.y);
    const int wf = (bid % NXCD) * ((MAXT * 16) / NXCD) + bid / NXCD;
    const int i = wf >> 4;
    if (i >= tlist[0]) return;
    const int o = tlist[1 + 2*i];
    mbase = tlist[2 + 2*i];
    r1 = offsets[o + 1];
    n0 = (wf & 15) * 64;
    W = W0 + (long long)o * wstride; bias = b0 + o * bstride; C = C0;
  }

  __shared__ unsigned short sAh[8192], sAl[8192], sBh[8192], sBl[8192];   // 64KB: 2 bufs x k64

  const int tid = threadIdx.x;
  const int wv = tid >> 6, lane = tid & 63;

  const int ar = tid & 63, akb = tid >> 6;
  int grow = mbase + ar;
  int arow = grow < r1 ? grow : mbase;
  if (GATHER) arow = order[arow];
  const unsigned short* pAh = Ahi + (long long)arow * lda;
  const unsigned short* pAl = Alo + (long long)arow * lda;

  const int qr = (wv >> 1) * 32, qc = (wv & 1) * 32;

  f32x4 acc[2][2];
#pragma unroll
  for (int a = 0; a < 2; a++)
#pragma unroll
    for (int b = 0; b < 2; b++) acc[a][b] = (f32x4){0.f, 0.f, 0.f, 0.f};

  float4 lah[2], lal[2];   // A staging regs (hi/lo, 2 k-blocks)
  float bv[16];            // B staging regs (fp32, wave's 16 k-rows)

#define LOADR(kt) {                                                          \
    _Pragma("unroll")                                                        \
    for (int h = 0; h < 2; h++){                                             \
      lah[h] = *(const float4*)(pAh + (kt) + (akb + h*4)*8);                 \
      lal[h] = *(const float4*)(pAl + (kt) + (akb + h*4)*8);                 \
    }                                                                        \
    _Pragma("unroll")                                                        \
    for (int rr = 0; rr < 16; rr++)                                          \
      bv[rr] = W[(long long)((kt) + wv*16 + rr) * N + n0 + lane]; }

#define WRITE(bf) {                                                          \
    const int bo = (bf) * 4096;                                              \
    _Pragma("unroll")                                                        \
    for (int h = 0; h < 2; h++){                                             \
      *(float4*)(sAh + bo + (akb + h*4)*512 + ar*8) = lah[h];                \
      *(float4*)(sAl + bo + (akb + h*4)*512 + ar*8) = lal[h];                \
    }                                                                        \
    _Pragma("unroll")                                                        \
    for (int rp = 0; rp < 8; rp++){                                          \
      const int kl = wv * 16 + rp * 2;                                       \
      const int kbl = kl >> 3, e = kl & 7;                                   \
      const unsigned short h0 = bf16_rne(bv[rp*2]), h1 = bf16_rne(bv[rp*2+1]); \
      const unsigned short l0 = bf16_rne(bv[rp*2] - bf16_tof(h0));           \
      const unsigned short l1 = bf16_rne(bv[rp*2+1] - bf16_tof(h1));         \
      *(unsigned*)(sBh + bo + kbl*512 + lane*8 + e) = ((unsigned)h1 << 16) | h0; \
      *(unsigned*)(sBl + bo + kbl*512 + lane*8 + e) = ((unsigned)l1 << 16) | l0; \
    } }

#define COMPUTE(bf) {                                                        \
    const int bo = (bf) * 4096;                                              \
    _Pragma("unroll")                                                        \
    for (int kg = 0; kg < 2; kg++){                                          \
      const int g = bo + (kg*4 + (lane >> 4)) * 512, li = lane & 15;         \
      bf16x8 a0h = *(const bf16x8*)(sAh + g + (qr + li) * 8);                \
      bf16x8 a1h = *(const bf16x8*)(sAh + g + (qr + 16 + li) * 8);           \
      bf16x8 a0l = *(const bf16x8*)(sAl + g + (qr + li) * 8);                \
      bf16x8 a1l = *(const bf16x8*)(sAl + g + (qr + 16 + li) * 8);           \
      bf16x8 b0h = *(const bf16x8*)(sBh + g + (qc + li) * 8);                \
      bf16x8 b1h = *(const bf16x8*)(sBh + g + (qc + 16 + li) * 8);           \
      bf16x8 b0l = *(const bf16x8*)(sBl + g + (qc + li) * 8);                \
      bf16x8 b1l = *(const bf16x8*)(sBl + g + (qc + 16 + li) * 8);           \
      acc[0][0] = __builtin_amdgcn_mfma_f32_16x16x32_bf16(a0h, b0h, acc[0][0], 0, 0, 0); \
      acc[0][1] = __builtin_amdgcn_mfma_f32_16x16x32_bf16(a0h, b1h, acc[0][1], 0, 0, 0); \
      acc[1][0] = __builtin_amdgcn_mfma_f32_16x16x32_bf16(a1h, b0h, acc[1][0], 0, 0, 0); \
      acc[1][1] = __builtin_amdgcn_mfma_f32_16x16x32_bf16(a1h, b1h, acc[1][1], 0, 0, 0); \
      acc[0][0] = __builtin_amdgcn_mfma_f32_16x16x32_bf16(a0h, b0l, acc[0][0], 0, 0, 0); \
      acc[0][1] = __builtin_amdgcn_mfma_f32_16x16x32_bf16(a0h, b1l, acc[0][1], 0, 0, 0); \
      acc[1][0] = __builtin_amdgcn_mfma_f32_16x16x32_bf16(a1h, b0l, acc[1][0], 0, 0, 0); \
      acc[1][1] = __builtin_amdgcn_mfma_f32_16x16x32_bf16(a1h, b1l, acc[1][1], 0, 0, 0); \
      acc[0][0] = __builtin_amdgcn_mfma_f32_16x16x32_bf16(a0l, b0h, acc[0][0], 0, 0, 0); \
      acc[0][1] = __builtin_amdgcn_mfma_f32_16x16x32_bf16(a0l, b1h, acc[0][1], 0, 0, 0); \
      acc[1][0] = __builtin_amdgcn_mfma_f32_16x16x32_bf16(a1l, b0h, acc[1][0], 0, 0, 0); \
      acc[1][1] = __builtin_amdgcn_mfma_f32_16x16x32_bf16(a1l, b1h, acc[1][1], 0, 0, 0); \
    } }

  LOADR(0); WRITE(0);
  __syncthreads();
  int buf = 0;
  for (int kt = 0; kt < K; kt += 64){
    const bool more = (kt + 64 < K);
    if (more) LOADR(kt + 64);        // loads in flight...
    COMPUTE(buf);                    // ...hidden under the MFMA burst
    if (more) WRITE(buf ^ 1);        // vmcnt wait lands here, after compute
    __syncthreads();
    buf ^= 1;
  }
#undef LOADR
#undef WRITE
#undef COMPUTE

#pragma unroll
  for (int rb = 0; rb < 2; rb++)
#pragma unroll
    for (int cb = 0; cb < 2; cb++){
      const int col = n0 + qc + cb*16 + (lane & 15);
      const float bvq = bias[col];
#pragma unroll
      for (int r = 0; r < 4; r++){
        const int row = mbase + qr + rb*16 + (lane >> 4)*4 + r;
        if (row < r1){
          const float v = fmaxf(acc[rb][cb][r] + bvq, 0.f);
          if (HILOOUT){
            const unsigned short h = bf16_rne(v);
            Chi[(long long)row * N + col] = h;
            Clo[(long long)row * N + col] = bf16_rne(v - bf16_tof(h));
          } else {
            C[(long long)row * N + col] = v;
          }
        }
      }
    }
}

// ---------------- q = h2 @ awo[o] (raw): grouped bf16x3 MFMA, N=64, split-K x4, T14 dbuf ----------
__global__ __launch_bounds__(256)
void q_mfma(const unsigned short* __restrict__ Ahi, const unsigned short* __restrict__ Alo,
            const float* __restrict__ awo,
            float* __restrict__ qp,
            const int* __restrict__ offsets, const int* __restrict__ tlist)
{
  const int i = blockIdx.x;
  if (i >= tlist[0]) return;
  const int o = tlist[1 + 2*i];
  const int mbase = tlist[2 + 2*i];
  const int r1 = offsets[o + 1];
  const int kb = blockIdx.y;
  const float* W = awo + (long long)o * Hdim * Aact;

  __shared__ unsigned short sAh[8192], sAl[8192], sBh[8192], sBl[8192];

  const int tid = threadIdx.x;
  const int wv = tid >> 6, lane = tid & 63;
  const int ar = tid & 63, akb = tid >> 6;
  int grow = mbase + ar;
  int arow = grow < r1 ? grow : mbase;
  const unsigned short* pAh = Ahi + (long long)arow * Hdim;
  const unsigned short* pAl = Alo + (long long)arow * Hdim;

  const int qr = (wv >> 1) * 32, qc = (wv & 1) * 32;

  f32x4 acc[2][2];
#pragma unroll
  for (int a = 0; a < 2; a++)
#pragma unroll
    for (int b = 0; b < 2; b++) acc[a][b] = (f32x4){0.f, 0.f, 0.f, 0.f};

  float4 lah[2], lal[2];
  float bv[16];

#define LOADR(kt) {                                                          \
    _Pragma("unroll")                                                        \
    for (int h = 0; h < 2; h++){                                             \
      lah[h] = *(const float4*)(pAh + (kt) + (akb + h*4)*8);                 \
      lal[h] = *(const float4*)(pAl + (kt) + (akb + h*4)*8);                 \
    }                                                                        \
    _Pragma("unroll")                                                        \
    for (int rr = 0; rr < 16; rr++)                                          \
      bv[rr] = W[((kt) + wv*16 + rr) * Aact + lane]; }

#define WRITE(bf) {                                                          \
    const int bo = (bf) * 4096;                                              \
    _Pragma("unroll")                                                        \
    for (int h = 0; h < 2; h++){                                             \
      *(float4*)(sAh + bo + (akb + h*4)*512 + ar*8) = lah[h];                \
      *(float4*)(sAl + bo + (akb + h*4)*512 + ar*8) = lal[h];                \
    }                                                                        \
    _Pragma("unroll")                                                        \
    for (int rp = 0; rp < 8; rp++){                                          \
      const int kl = wv * 16 + rp * 2;                                       \
      const int kbl = kl >> 3, e = kl & 7;                                   \
      const unsigned short h0 = bf16_rne(bv[rp*2]), h1 = bf16_rne(bv[rp*2+1]); \
      const unsigned short l0 = bf16_rne(bv[rp*2] - bf16_tof(h0));           \
      const unsigned short l1 = bf16_rne(bv[rp*2+1] - bf16_tof(h1));         \
      *(unsigned*)(sBh + bo + kbl*512 + lane*8 + e) = ((unsigned)h1 << 16) | h0; \
      *(unsigned*)(sBl + bo + kbl*512 + lane*8 + e) = ((unsigned)l1 << 16) | l0; \
    } }

#define COMPUTE(bf) {                                                        \
    const int bo = (bf) * 4096;                                              \
    _Pragma("unroll")                                                        \
    for (int kg = 0; kg < 2; kg++){                                          \
      const int g = bo + (kg*4 + (lane >> 4)) * 512, li = lane & 15;         \
      bf16x8 a0h = *(const bf16x8*)(sAh + g + (qr + li) * 8);                \
      bf16x8 a1h = *(const bf16x8*)(sAh + g + (qr + 16 + li) * 8);           \
      bf16x8 a0l = *(const bf16x8*)(sAl + g + (qr + li) * 8);                \
      bf16x8 a1l = *(const bf16x8*)(sAl + g + (qr + 16 + li) * 8);           \
      bf16x8 b0h = *(const bf16x8*)(sBh + g + (qc + li) * 8);                \
      bf16x8 b1h = *(const bf16x8*)(sBh + g + (qc + 16 + li) * 8);           \
      bf16x8 b0l = *(const bf16x8*)(sBl + g + (qc + li) * 8);                \
      bf16x8 b1l = *(const bf16x8*)(sBl + g + (qc + 16 + li) * 8);           \
      acc[0][0] = __builtin_amdgcn_mfma_f32_16x16x32_bf16(a0h, b0h, acc[0][0], 0, 0, 0); \
      acc[0][1] = __builtin_amdgcn_mfma_f32_16x16x32_bf16(a0h, b1h, acc[0][1], 0, 0, 0); \
      acc[1][0] = __builtin_amdgcn_mfma_f32_16x16x32_bf16(a1h, b0h, acc[1][0], 0, 0, 0); \
      acc[1][1] = __builtin_amdgcn_mfma_f32_16x16x32_bf16(a1h, b1h, acc[1][1], 0, 0, 0); \
      acc[0][0] = __builtin_amdgcn_mfma_f32_16x16x32_bf16(a0h, b0l, acc[0][0], 0, 0, 0); \
      acc[0][1] = __builtin_amdgcn_mfma_f32_16x16x32_bf16(a0h, b1l, acc[0][1], 0, 0, 0); \
      acc[1][0] = __builtin_amdgcn_mfma_f32_16x16x32_bf16(a1h, b0l, acc[1][0], 0, 0, 0); \
      acc[1][1] = __builtin_amdgcn_mfma_f32_16x16x32_bf16(a1h, b1l, acc[1][1], 0, 0, 0); \
      acc[0][0] = __builtin_amdgcn_mfma_f32_16x16x32_bf16(a0l, b0h, acc[0][0], 0, 0, 0); \
      acc[0][1] = __builtin_amdgcn_mfma_f32_16x16x32_bf16(a0l, b1h, acc[0][1], 0, 0, 0); \
      acc[1][0] = __builtin_amdgcn_mfma_f32_16x16x32_bf16(a1l, b0h, acc[1][0], 0, 0, 0); \
      acc[1][1] = __builtin_amdgcn_mfma_f32_16x16x32_bf16(a1l, b1h, acc[1][1], 0, 0, 0); \
    } }

  const int kbeg = kb * 256, kend = kbeg + 256;
  LOADR(kbeg); WRITE(0);
  __syncthreads();
  int buf = 0;
  for (int kt = kbeg; kt < kend; kt += 64){
    const bool more = (kt + 64 < kend);
    if (more) LOADR(kt + 64);
    COMPUTE(buf);
    if (more) WRITE(buf ^ 1);
    __syncthreads();
    buf ^= 1;
  }
#undef LOADR
#undef WRITE
#undef COMPUTE

#pragma unroll
  for (int rb = 0; rb < 2; rb++)
#pragma unroll
    for (int cb = 0; cb < 2; cb++){
      const int col = qc + cb*16 + (lane & 15);
#pragma unroll
      for (int r = 0; r < 4; r++){
        const int row = mbase + qr + rb*16 + (lane >> 4)*4 + r;
        if (row < r1)
          qp[((long long)kb * Bsz + row) * Aact + col] = acc[rb][cb][r];
      }
    }
}

// ---------------- per-row action head: q = sum(qp) + abo[o], softmax, argmax (1 wave/row) ----------
__global__ __launch_bounds__(64)
void act_kernel(const float* __restrict__ qp, const float* __restrict__ abo,
                const int* __restrict__ order, const int* __restrict__ offsets,
                float* __restrict__ out)
{
  const int r = blockIdx.x;
  int o = 0;
#pragma unroll
  for (int i = 1; i < 8; ++i) if (offsets[i] <= r) o = i;
  const int a = threadIdx.x;
  const long long idx = (long long)r * Aact + a;
  float q = qp[idx] + qp[(long long)Bsz*Aact + idx] + qp[2ll*Bsz*Aact + idx]
          + qp[3ll*Bsz*Aact + idx] + abo[o * Aact + a];
  float m = q;
#pragma unroll
  for (int off = 32; off; off >>= 1) m = fmaxf(m, __shfl_xor(m, off));
  float e = expf(q - m);
  float s = e;
#pragma unroll
  for (int off = 32; off; off >>= 1) s += __shfl_xor(s, off);
  const int b = order[r];
  out[OFF_ACT + b * Aact + a] = e / s;
  unsigned long long msk = __ballot(q == m);
  if (a == 0) out[OFF_SACT + b] = (float)__builtin_ctzll(msk);
}

// ---------------- per-row head: opt logits + softmax + argmax + gumbel sel + termination ----------------
__global__ __launch_bounds__(256)
void head_kernel(const float* __restrict__ h1, const float* __restrict__ th,
                 const float* __restrict__ ow2, const float* __restrict__ ob2,
                 const float* __restrict__ tw2, const float* __restrict__ tb2,
                 float* __restrict__ out, int* __restrict__ sel)
{
  const int b = blockIdx.x;
  const int t = threadIdx.x;
  const float* hrow = h1 + b * Hdim;
  const float* trow = th + b * Hdim;

  float acc[8] = {}; float accT = 0.f;
  for (int k = t; k < Hdim; k += 256){
    float hv = hrow[k];
    const float* w = ow2 + k * 8;
#pragma unroll
    for (int o2 = 0; o2 < 8; ++o2) acc[o2] += hv * w[o2];
    accT += trow[k] * tw2[k];
  }
#pragma unroll
  for (int o2 = 0; o2 < 8; ++o2)
    for (int off = 32; off; off >>= 1) acc[o2] += __shfl_down(acc[o2], off);
  for (int off = 32; off; off >>= 1) accT += __shfl_down(accT, off);

  __shared__ float wred[4][9];
  __shared__ float logits[8];
  __shared__ float gum[8];
  const int wave = t >> 6, lane = t & 63;
  if (lane == 0){
#pragma unroll
    for (int o2 = 0; o2 < 8; ++o2) wred[wave][o2] = acc[o2];
    wred[wave][8] = accT;
  }
  __syncthreads();
  if (t < 9){
    float s = wred[0][t] + wred[1][t] + wred[2][t] + wred[3][t];
    if (t < 8) logits[t] = s + ob2[t];
    else       out[OFF_TERM + b] = 1.f / (1.f + expf(-(s + tb2[0])));
  }
  __syncthreads();
  if (t < 8) gum[t] = logits[t] + gumbel_at(b * 8 + t);
  __syncthreads();
  if (t == 0){
    float m = logits[0]; int am = 0;
#pragma unroll
    for (int o2 = 1; o2 < 8; ++o2) if (logits[o2] > m){ m = logits[o2]; am = o2; }
    float p[8]; float s = 0.f;
#pragma unroll
    for (int o2 = 0; o2 < 8; ++o2){ p[o2] = expf(logits[o2] - m); s += p[o2]; }
    float inv = 1.f / s;
#pragma unroll
    for (int o2 = 0; o2 < 8; ++o2) out[b * 8 + o2] = p[o2] * inv;
    out[OFF_OARG + b] = (float)am;
    float gm = gum[0]; int gs = 0;
#pragma unroll
    for (int o2 = 1; o2 < 8; ++o2) if (gum[o2] > gm){ gm = gum[o2]; gs = o2; }
    sel[b] = gs;
  }
}

// ---------------- routing: bucket samples by expert + emit row-tile list ----------------
__global__ void route_kernel(const int* __restrict__ sel, int* __restrict__ order,
                             int* __restrict__ offsets, int* __restrict__ tlist)
{
  __shared__ int cnt[8];
  __shared__ int base[8];
  const int t = threadIdx.x;
  if (t < 8) cnt[t] = 0;
  __syncthreads();
  const int s = sel[t];
  atomicAdd(&cnt[s], 1);
  __syncthreads();
  if (t == 0){
    int a = 0;
    for (int o = 0; o < 8; ++o){ offsets[o] = a; base[o] = a; a += cnt[o]; }
    offsets[8] = a;
    int nt = 0;
    for (int o = 0; o < 8; ++o)
      for (int mb = offsets[o]; mb < offsets[o] + cnt[o]; mb += 64){
        tlist[1 + 2*nt] = o; tlist[2 + 2*nt] = mb; ++nt;
      }
    tlist[0] = nt;
  }
  __syncthreads();
  const int pos = atomicAdd(&base[s], 1);
  order[pos] = t;   // permutation within an expert is nondeterministic; outputs don't depend on it
}

extern "C" void kernel_launch(void* const* d_in, const int* in_sizes, int n_in,
                              void* d_out, int out_size, void* d_ws, size_t ws_size,
                              hipStream_t stream)
{
  (void)in_sizes; (void)n_in; (void)out_size; (void)ws_size;
  const float* state = (const float*)d_in[0];
  const float* ow1   = (const float*)d_in[1];
  const float* ob1   = (const float*)d_in[2];
  const float* ow2   = (const float*)d_in[3];
  const float* ob2   = (const float*)d_in[4];
  const float* aw1   = (const float*)d_in[5];
  const float* ab1   = (const float*)d_in[6];
  const float* awh   = (const float*)d_in[7];
  const float* abh   = (const float*)d_in[8];
  const float* awo   = (const float*)d_in[9];
  const float* abo   = (const float*)d_in[10];
  const float* tw1   = (const float*)d_in[11];
  const float* tb1   = (const float*)d_in[12];
  const float* tw2   = (const float*)d_in[13];
  const float* tb2   = (const float*)d_in[14];
  float* out = (float*)d_out;

  float* h1 = (float*)d_ws;                                 // dense opt hidden (fp32)
  float* h2 = h1 + (long long)Bsz * Hdim;                   // dense term hidden (fp32)
  float* qp = h2 + (long long)Bsz * Hdim;                   // q partials [4][1024][64]
  unsigned short* sthi = (unsigned short*)(qp + 4ll * Bsz * Aact);  // state hi [1024][512]
  unsigned short* stlo = sthi + (long long)Bsz * Din;
  unsigned short* h1hi = stlo + (long long)Bsz * Din;       // L1 out hi/lo [1024][1024]
  unsigned short* h1lo = h1hi + (long long)Bsz * Hdim;
  unsigned short* h2hi = h1lo + (long long)Bsz * Hdim;      // L2 out hi/lo [1024][1024]
  unsigned short* h2lo = h2hi + (long long)Bsz * Hdim;
  int* sel     = (int*)(h2lo + (long long)Bsz * Hdim);
  int* order   = sel + Bsz;
  int* offsets = order + Bsz;
  int* tlist   = offsets + 9;           // [ntiles | (expert,mbase) * MAXT]

  // 1. state -> hi/lo bf16
  convert_state<<<dim3(512), 256, 0, stream>>>(state, sthi, stlo);
  // 2. dense pair: h1 = relu(st @ ow1 + ob1), h2 = relu(st @ tw1 + tb1)
  mfma_gemm<true, false, false><<<dim3(16, 16, 2), 256, 0, stream>>>(
      sthi, stlo, Din, ow1, tw1, 0, ob1, tb1, 0, h1, h2, nullptr, nullptr,
      Hdim, Din, nullptr, nullptr, nullptr);
  // 3. heads: opt softmax/argmax, gumbel categorical sel, termination sigmoid
  head_kernel<<<dim3(Bsz), 256, 0, stream>>>(h1, h2, ow2, ob2, tw2, tb2, out, sel);
  // 4. bucket samples by expert + tile list
  route_kernel<<<dim3(1), 1024, 0, stream>>>(sel, order, offsets, tlist);
  // 5. expert L1 (gather state rows): h1hi/lo[r] = split(relu(state[order[r]] @ aw1[o] + ab1[o]))
  mfma_gemm<false, true, true><<<dim3(MAXT, 16), 256, 0, stream>>>(
      sthi, stlo, Din, aw1, nullptr, (long long)Din*Hdim, ab1, nullptr, Hdim,
      nullptr, nullptr, h1hi, h1lo, Hdim, Din, order, offsets, tlist);
  // 6. expert L2: h2hi/lo[r] = split(relu(h1[r] @ awh[o,0] + abh[o,0]))
  mfma_gemm<false, false, true><<<dim3(MAXT, 16), 256, 0, stream>>>(
      h1hi, h1lo, Hdim, awh, nullptr, (long long)Hdim*Hdim, abh, nullptr, Hdim,
      nullptr, nullptr, h2hi, h2lo, Hdim, Hdim, nullptr, offsets, tlist);
  // 7. q partials: qp[kb] = h2 @ awo[o] (chunk kb of K)   [MFMA, split-K x4, T14 dbuf]
  q_mfma<<<dim3(MAXT, 4), 256, 0, stream>>>(h2hi, h2lo, awo, qp, offsets, tlist);
  // 8. action head: q = sum(qp)+abo, softmax, argmax
  act_kernel<<<dim3(Bsz), 64, 0, stream>>>(qp, abo, order, offsets, out);
}

// Round 26
// 106.748 us; speedup vs baseline: 1.7358x; 1.7358x over previous
//
#include <hip/hip_runtime.h>
#include <math.h>

#define Bsz 1024
#define Din 512
#define Hdim 1024
#define Aact 64
#define MAXT 23   // max row-tiles across experts: 7 partial + 16
#define NXCD 8

// out layout (float32): option_probs[1024*8] | action_probs[1024*64] | term[1024] | opt_argmax[1024] | sel_action[1024]
#define OFF_ACT   8192
#define OFF_TERM  73728
#define OFF_OARG  74752
#define OFF_SACT  75776

typedef __attribute__((ext_vector_type(8))) short bf16x8;
typedef __attribute__((ext_vector_type(4))) float f32x4;

// ---------------- threefry2x32-20, key (0,42), partitionable XOR-fold (verified R3-R25) ----------------
__device__ __forceinline__ unsigned rotl32(unsigned x, int d){ return (x << d) | (x >> (32 - d)); }

__device__ __forceinline__ void threefry_042(unsigned& x0, unsigned& x1){
  const unsigned ks0 = 0u, ks1 = 42u, ks2 = 0x1BD11BDAu ^ 0u ^ 42u;
  x0 += ks0; x1 += ks1;
#define TFR(r) { x0 += x1; x1 = rotl32(x1, r); x1 ^= x0; }
  TFR(13) TFR(15) TFR(26) TFR(6)  x0 += ks1; x1 += ks2 + 1u;
  TFR(17) TFR(29) TFR(16) TFR(24) x0 += ks2; x1 += ks0 + 2u;
  TFR(13) TFR(15) TFR(26) TFR(6)  x0 += ks0; x1 += ks1 + 3u;
  TFR(17) TFR(29) TFR(16) TFR(24) x0 += ks1; x1 += ks2 + 4u;
  TFR(13) TFR(15) TFR(26) TFR(6)  x0 += ks2; x1 += ks0 + 5u;
#undef TFR
}

__device__ __forceinline__ float gumbel_at(int idx){
  unsigned x0 = 0u, x1 = (unsigned)idx;
  threefry_042(x0, x1);
  unsigned bits = x0 ^ x1;
  float f = __uint_as_float((bits >> 9) | 0x3F800000u) - 1.0f;
  float u = fmaxf(f, 1.1754944e-38f);
  return -logf(-logf(u));
}

// ---------------- bf16 hi/lo split helpers (RNE) ----------------
__device__ __forceinline__ unsigned short bf16_rne(float x){
  unsigned u = __float_as_uint(x);
  return (unsigned short)((u + 0x7FFFu + ((u >> 16) & 1u)) >> 16);
}
__device__ __forceinline__ float bf16_tof(unsigned short h){
  return __uint_as_float(((unsigned)h) << 16);
}

// ---------------- state -> hi/lo bf16 (row-major, same indexing) ----------------
__global__ __launch_bounds__(256)
void convert_state(const float* __restrict__ st, unsigned short* __restrict__ hi,
                   unsigned short* __restrict__ lo)
{
  const int i = (blockIdx.x * 256 + threadIdx.x) * 4;
  float4 v = *(const float4*)(st + i);
  ushort4 h, l;
  h.x = bf16_rne(v.x); l.x = bf16_rne(v.x - bf16_tof(h.x));
  h.y = bf16_rne(v.y); l.y = bf16_rne(v.y - bf16_tof(h.y));
  h.z = bf16_rne(v.z); l.z = bf16_rne(v.z - bf16_tof(h.z));
  h.w = bf16_rne(v.w); l.w = bf16_rne(v.w - bf16_tof(h.w));
  *(ushort4*)(hi + i) = h;
  *(ushort4*)(lo + i) = l;
}

// ---------------- bf16x3 MFMA GEMM: 64x64 tile, 4 waves = 32x32 quadrants, k-step 64 ----------------
// R26 = R23's proven kernel (2-barrier, 32KB LDS) + RAW dense mode: global split-K x2
// (grid (16,16,4)=1024 blocks=4/CU, kb computes K/2 raw sums; bias+relu folded into head).
// R24/R25 scheduling experiments falsified; TLP (blocks/CU) is the proven lever (R15/R16).
// a*b ~= ahi*bhi + ahi*blo + alo*bhi (fp32 MFMA accum); error class == fp32 split-K reorder.
// mfma_f32_16x16x32_bf16 layouts: A row=l&15,k=(l>>4)*8+e; B col=l&15; D col=l&15,row=(l>>4)*4+r.
template<bool DENSE, bool GATHER, bool HILOOUT, bool RAW>
__global__ __launch_bounds__(256)
void mfma_gemm(const unsigned short* __restrict__ Ahi, const unsigned short* __restrict__ Alo,
               int lda,
               const float* __restrict__ W0, const float* __restrict__ W1, long long wstride,
               const float* __restrict__ b0, const float* __restrict__ b1, int bstride,
               float* __restrict__ C0, float* __restrict__ C1,
               float* __restrict__ P0, float* __restrict__ P1,
               unsigned short* __restrict__ Chi, unsigned short* __restrict__ Clo,
               int N, int K,
               const int* __restrict__ order, const int* __restrict__ offsets,
               const int* __restrict__ tlist)
{
  const float* W; const float* bias = nullptr; float* C;
  int mbase, r1, n0, kbeg, kend;
  if (DENSE){
    // RAW: 1024 blocks -> {net, kb, 16 m, 16 n}; bijective XCD swizzle, chunk 128/XCD
    const int bid = (int)(blockIdx.x + 16u*blockIdx.y + 256u*blockIdx.z);
    const int wf = (bid & 7) * (RAW ? 128 : 64) + (bid >> 3);
    const int ny = wf & 15, mx = (wf >> 4) & 15, zz = wf >> 8;
    const int net = RAW ? (zz & 1) : zz;
    const int kb = RAW ? (zz >> 1) : 0;
    mbase = mx * 64; r1 = Bsz; n0 = ny * 64;
    W = net ? W1 : W0;
    if (RAW){ C = kb ? (net ? P1 : P0) : (net ? C1 : C0); }
    else    { bias = net ? b1 : b0; C = net ? C1 : C0; }
    kbeg = kb * (RAW ? (K >> 1) : K); kend = kbeg + (RAW ? (K >> 1) : K);
  } else {
    const int bid = (int)(blockIdx.x + gridDim.x * blockIdx.y);
    const int wf = (bid % NXCD) * ((MAXT * 16) / NXCD) + bid / NXCD;
    const int i = wf >> 4;
    if (i >= tlist[0]) return;
    const int o = tlist[1 + 2*i];
    mbase = tlist[2 + 2*i];
    r1 = offsets[o + 1];
    n0 = (wf & 15) * 64;
    W = W0 + (long long)o * wstride; bias = b0 + o * bstride; C = C0;
    kbeg = 0; kend = K;
  }

  __shared__ unsigned short sAh[4096], sAl[4096], sBh[4096], sBl[4096];   // 32KB, k-step 64

  const int tid = threadIdx.x;
  const int wv = tid >> 6, lane = tid & 63;

  const int ar = tid & 63, akb = tid >> 6;
  int grow = mbase + ar;
  int arow = grow < r1 ? grow : mbase;
  if (GATHER) arow = order[arow];
  const unsigned short* pAh = Ahi + (long long)arow * lda;
  const unsigned short* pAl = Alo + (long long)arow * lda;

  const int qr = (wv >> 1) * 32, qc = (wv & 1) * 32;

  f32x4 acc[2][2];
#pragma unroll
  for (int a = 0; a < 2; a++)
#pragma unroll
    for (int b = 0; b < 2; b++) acc[a][b] = (f32x4){0.f, 0.f, 0.f, 0.f};

  for (int kt = kbeg; kt < kend; kt += 64){
#pragma unroll
    for (int h = 0; h < 2; h++){
      const int kbl = akb + h*4;
      *(float4*)(sAh + kbl*512 + ar*8) = *(const float4*)(pAh + kt + kbl*8);
      *(float4*)(sAl + kbl*512 + ar*8) = *(const float4*)(pAl + kt + kbl*8);
    }
#pragma unroll
    for (int rp = 0; rp < 8; rp++){
      const int kl = wv * 16 + rp * 2;
      const int kbl = kl >> 3, e = kl & 7;
      const float v0 = W[(long long)(kt + kl) * N + n0 + lane];
      const float v1 = W[(long long)(kt + kl + 1) * N + n0 + lane];
      const unsigned short h0 = bf16_rne(v0), h1 = bf16_rne(v1);
      const unsigned short l0 = bf16_rne(v0 - bf16_tof(h0)), l1 = bf16_rne(v1 - bf16_tof(h1));
      *(unsigned*)(sBh + kbl*512 + lane*8 + e) = ((unsigned)h1 << 16) | h0;
      *(unsigned*)(sBl + kbl*512 + lane*8 + e) = ((unsigned)l1 << 16) | l0;
    }
    __syncthreads();
#pragma unroll
    for (int kg = 0; kg < 2; kg++){
      const int g = (kg*4 + (lane >> 4)) * 512, li = lane & 15;
      bf16x8 a0h = *(const bf16x8*)(sAh + g + (qr + li) * 8);
      bf16x8 a1h = *(const bf16x8*)(sAh + g + (qr + 16 + li) * 8);
      bf16x8 a0l = *(const bf16x8*)(sAl + g + (qr + li) * 8);
      bf16x8 a1l = *(const bf16x8*)(sAl + g + (qr + 16 + li) * 8);
      bf16x8 b0h = *(const bf16x8*)(sBh + g + (qc + li) * 8);
      bf16x8 b1h = *(const bf16x8*)(sBh + g + (qc + 16 + li) * 8);
      bf16x8 b0l = *(const bf16x8*)(sBl + g + (qc + li) * 8);
      bf16x8 b1l = *(const bf16x8*)(sBl + g + (qc + 16 + li) * 8);
      acc[0][0] = __builtin_amdgcn_mfma_f32_16x16x32_bf16(a0h, b0h, acc[0][0], 0, 0, 0);
      acc[0][1] = __builtin_amdgcn_mfma_f32_16x16x32_bf16(a0h, b1h, acc[0][1], 0, 0, 0);
      acc[1][0] = __builtin_amdgcn_mfma_f32_16x16x32_bf16(a1h, b0h, acc[1][0], 0, 0, 0);
      acc[1][1] = __builtin_amdgcn_mfma_f32_16x16x32_bf16(a1h, b1h, acc[1][1], 0, 0, 0);
      acc[0][0] = __builtin_amdgcn_mfma_f32_16x16x32_bf16(a0h, b0l, acc[0][0], 0, 0, 0);
      acc[0][1] = __builtin_amdgcn_mfma_f32_16x16x32_bf16(a0h, b1l, acc[0][1], 0, 0, 0);
      acc[1][0] = __builtin_amdgcn_mfma_f32_16x16x32_bf16(a1h, b0l, acc[1][0], 0, 0, 0);
      acc[1][1] = __builtin_amdgcn_mfma_f32_16x16x32_bf16(a1h, b1l, acc[1][1], 0, 0, 0);
      acc[0][0] = __builtin_amdgcn_mfma_f32_16x16x32_bf16(a0l, b0h, acc[0][0], 0, 0, 0);
      acc[0][1] = __builtin_amdgcn_mfma_f32_16x16x32_bf16(a0l, b1h, acc[0][1], 0, 0, 0);
      acc[1][0] = __builtin_amdgcn_mfma_f32_16x16x32_bf16(a1l, b0h, acc[1][0], 0, 0, 0);
      acc[1][1] = __builtin_amdgcn_mfma_f32_16x16x32_bf16(a1l, b1h, acc[1][1], 0, 0, 0);
    }
    __syncthreads();
  }

#pragma unroll
  for (int rb = 0; rb < 2; rb++)
#pragma unroll
    for (int cb = 0; cb < 2; cb++){
      const int col = n0 + qc + cb*16 + (lane & 15);
      const float bv = RAW ? 0.f : bias[col];
#pragma unroll
      for (int r = 0; r < 4; r++){
        const int row = mbase + qr + rb*16 + (lane >> 4)*4 + r;
        if (row < r1){
          if (RAW){
            C[(long long)row * N + col] = acc[rb][cb][r];
          } else {
            const float v = fmaxf(acc[rb][cb][r] + bv, 0.f);
            if (HILOOUT){
              const unsigned short h = bf16_rne(v);
              Chi[(long long)row * N + col] = h;
              Clo[(long long)row * N + col] = bf16_rne(v - bf16_tof(h));
            } else {
              C[(long long)row * N + col] = v;
            }
          }
        }
      }
    }
}

// ---------------- q = h2 @ awo[o] (raw): grouped bf16x3 MFMA, N=64, split-K x4 (R23 verbatim) ----
__global__ __launch_bounds__(256)
void q_mfma(const unsigned short* __restrict__ Ahi, const unsigned short* __restrict__ Alo,
            const float* __restrict__ awo,
            float* __restrict__ qp,
            const int* __restrict__ offsets, const int* __restrict__ tlist)
{
  const int i = blockIdx.x;
  if (i >= tlist[0]) return;
  const int o = tlist[1 + 2*i];
  const int mbase = tlist[2 + 2*i];
  const int r1 = offsets[o + 1];
  const int kb = blockIdx.y;
  const float* W = awo + (long long)o * Hdim * Aact;

  __shared__ unsigned short sAh[4096], sAl[4096], sBh[4096], sBl[4096];

  const int tid = threadIdx.x;
  const int wv = tid >> 6, lane = tid & 63;
  const int ar = tid & 63, akb = tid >> 6;
  int grow = mbase + ar;
  int arow = grow < r1 ? grow : mbase;
  const unsigned short* pAh = Ahi + (long long)arow * Hdim;
  const unsigned short* pAl = Alo + (long long)arow * Hdim;

  const int qr = (wv >> 1) * 32, qc = (wv & 1) * 32;

  f32x4 acc[2][2];
#pragma unroll
  for (int a = 0; a < 2; a++)
#pragma unroll
    for (int b = 0; b < 2; b++) acc[a][b] = (f32x4){0.f, 0.f, 0.f, 0.f};

  const int kbeg = kb * 256, kend = kbeg + 256;
  for (int kt = kbeg; kt < kend; kt += 64){
#pragma unroll
    for (int h = 0; h < 2; h++){
      const int kbl = akb + h*4;
      *(float4*)(sAh + kbl*512 + ar*8) = *(const float4*)(pAh + kt + kbl*8);
      *(float4*)(sAl + kbl*512 + ar*8) = *(const float4*)(pAl + kt + kbl*8);
    }
#pragma unroll
    for (int rp = 0; rp < 8; rp++){
      const int kl = wv * 16 + rp * 2;
      const int kbl = kl >> 3, e = kl & 7;
      const float v0 = W[(kt + kl) * Aact + lane];
      const float v1 = W[(kt + kl + 1) * Aact + lane];
      const unsigned short h0 = bf16_rne(v0), h1 = bf16_rne(v1);
      const unsigned short l0 = bf16_rne(v0 - bf16_tof(h0)), l1 = bf16_rne(v1 - bf16_tof(h1));
      *(unsigned*)(sBh + kbl*512 + lane*8 + e) = ((unsigned)h1 << 16) | h0;
      *(unsigned*)(sBl + kbl*512 + lane*8 + e) = ((unsigned)l1 << 16) | l0;
    }
    __syncthreads();
#pragma unroll
    for (int kg = 0; kg < 2; kg++){
      const int g = (kg*4 + (lane >> 4)) * 512, li = lane & 15;
      bf16x8 a0h = *(const bf16x8*)(sAh + g + (qr + li) * 8);
      bf16x8 a1h = *(const bf16x8*)(sAh + g + (qr + 16 + li) * 8);
      bf16x8 a0l = *(const bf16x8*)(sAl + g + (qr + li) * 8);
      bf16x8 a1l = *(const bf16x8*)(sAl + g + (qr + 16 + li) * 8);
      bf16x8 b0h = *(const bf16x8*)(sBh + g + (qc + li) * 8);
      bf16x8 b1h = *(const bf16x8*)(sBh + g + (qc + 16 + li) * 8);
      bf16x8 b0l = *(const bf16x8*)(sBl + g + (qc + li) * 8);
      bf16x8 b1l = *(const bf16x8*)(sBl + g + (qc + 16 + li) * 8);
      acc[0][0] = __builtin_amdgcn_mfma_f32_16x16x32_bf16(a0h, b0h, acc[0][0], 0, 0, 0);
      acc[0][1] = __builtin_amdgcn_mfma_f32_16x16x32_bf16(a0h, b1h, acc[0][1], 0, 0, 0);
      acc[1][0] = __builtin_amdgcn_mfma_f32_16x16x32_bf16(a1h, b0h, acc[1][0], 0, 0, 0);
      acc[1][1] = __builtin_amdgcn_mfma_f32_16x16x32_bf16(a1h, b1h, acc[1][1], 0, 0, 0);
      acc[0][0] = __builtin_amdgcn_mfma_f32_16x16x32_bf16(a0h, b0l, acc[0][0], 0, 0, 0);
      acc[0][1] = __builtin_amdgcn_mfma_f32_16x16x32_bf16(a0h, b1l, acc[0][1], 0, 0, 0);
      acc[1][0] = __builtin_amdgcn_mfma_f32_16x16x32_bf16(a1h, b0l, acc[1][0], 0, 0, 0);
      acc[1][1] = __builtin_amdgcn_mfma_f32_16x16x32_bf16(a1h, b1l, acc[1][1], 0, 0, 0);
      acc[0][0] = __builtin_amdgcn_mfma_f32_16x16x32_bf16(a0l, b0h, acc[0][0], 0, 0, 0);
      acc[0][1] = __builtin_amdgcn_mfma_f32_16x16x32_bf16(a0l, b1h, acc[0][1], 0, 0, 0);
      acc[1][0] = __builtin_amdgcn_mfma_f32_16x16x32_bf16(a1l, b0h, acc[1][0], 0, 0, 0);
      acc[1][1] = __builtin_amdgcn_mfma_f32_16x16x32_bf16(a1l, b1h, acc[1][1], 0, 0, 0);
    }
    __syncthreads();
  }

#pragma unroll
  for (int rb = 0; rb < 2; rb++)
#pragma unroll
    for (int cb = 0; cb < 2; cb++){
      const int col = qc + cb*16 + (lane & 15);
#pragma unroll
      for (int r = 0; r < 4; r++){
        const int row = mbase + qr + rb*16 + (lane >> 4)*4 + r;
        if (row < r1)
          qp[((long long)kb * Bsz + row) * Aact + col] = acc[rb][cb][r];
      }
    }
}

// ---------------- per-row action head: q = sum(qp) + abo[o], softmax, argmax (1 wave/row) ----------
__global__ __launch_bounds__(64)
void act_kernel(const float* __restrict__ qp, const float* __restrict__ abo,
                const int* __restrict__ order, const int* __restrict__ offsets,
                float* __restrict__ out)
{
  const int r = blockIdx.x;
  int o = 0;
#pragma unroll
  for (int i = 1; i < 8; ++i) if (offsets[i] <= r) o = i;
  const int a = threadIdx.x;
  const long long idx = (long long)r * Aact + a;
  float q = qp[idx] + qp[(long long)Bsz*Aact + idx] + qp[2ll*Bsz*Aact + idx]
          + qp[3ll*Bsz*Aact + idx] + abo[o * Aact + a];
  float m = q;
#pragma unroll
  for (int off = 32; off; off >>= 1) m = fmaxf(m, __shfl_xor(m, off));
  float e = expf(q - m);
  float s = e;
#pragma unroll
  for (int off = 32; off; off >>= 1) s += __shfl_xor(s, off);
  const int b = order[r];
  out[OFF_ACT + b * Aact + a] = e / s;
  unsigned long long msk = __ballot(q == m);
  if (a == 0) out[OFF_SACT + b] = (float)__builtin_ctzll(msk);
}

// ---------------- per-row head: folds relu(ba+bb+ob1)/relu(bc+bd+tb1) (verified R17/R19) ----------
__global__ __launch_bounds__(256)
void head_kernel(const float* __restrict__ ba, const float* __restrict__ bb,
                 const float* __restrict__ bc, const float* __restrict__ bd,
                 const float* __restrict__ ob1, const float* __restrict__ tb1,
                 const float* __restrict__ ow2, const float* __restrict__ ob2,
                 const float* __restrict__ tw2, const float* __restrict__ tb2,
                 float* __restrict__ out, int* __restrict__ sel)
{
  const int b = blockIdx.x;
  const int t = threadIdx.x;
  const long long rb = (long long)b * Hdim;

  float acc[8] = {}; float accT = 0.f;
  for (int k = t; k < Hdim; k += 256){
    float hv = fmaxf(ba[rb + k] + bb[rb + k] + ob1[k], 0.f);
    float tv = fmaxf(bc[rb + k] + bd[rb + k] + tb1[k], 0.f);
    const float* w = ow2 + k * 8;
#pragma unroll
    for (int o2 = 0; o2 < 8; ++o2) acc[o2] += hv * w[o2];
    accT += tv * tw2[k];
  }
#pragma unroll
  for (int o2 = 0; o2 < 8; ++o2)
    for (int off = 32; off; off >>= 1) acc[o2] += __shfl_down(acc[o2], off);
  for (int off = 32; off; off >>= 1) accT += __shfl_down(accT, off);

  __shared__ float wred[4][9];
  __shared__ float logits[8];
  __shared__ float gum[8];
  const int wave = t >> 6, lane = t & 63;
  if (lane == 0){
#pragma unroll
    for (int o2 = 0; o2 < 8; ++o2) wred[wave][o2] = acc[o2];
    wred[wave][8] = accT;
  }
  __syncthreads();
  if (t < 9){
    float s = wred[0][t] + wred[1][t] + wred[2][t] + wred[3][t];
    if (t < 8) logits[t] = s + ob2[t];
    else       out[OFF_TERM + b] = 1.f / (1.f + expf(-(s + tb2[0])));
  }
  __syncthreads();
  if (t < 8) gum[t] = logits[t] + gumbel_at(b * 8 + t);
  __syncthreads();
  if (t == 0){
    float m = logits[0]; int am = 0;
#pragma unroll
    for (int o2 = 1; o2 < 8; ++o2) if (logits[o2] > m){ m = logits[o2]; am = o2; }
    float p[8]; float s = 0.f;
#pragma unroll
    for (int o2 = 0; o2 < 8; ++o2){ p[o2] = expf(logits[o2] - m); s += p[o2]; }
    float inv = 1.f / s;
#pragma unroll
    for (int o2 = 0; o2 < 8; ++o2) out[b * 8 + o2] = p[o2] * inv;
    out[OFF_OARG + b] = (float)am;
    float gm = gum[0]; int gs = 0;
#pragma unroll
    for (int o2 = 1; o2 < 8; ++o2) if (gum[o2] > gm){ gm = gum[o2]; gs = o2; }
    sel[b] = gs;
  }
}

// ---------------- routing: bucket samples by expert + emit row-tile list ----------------
__global__ void route_kernel(const int* __restrict__ sel, int* __restrict__ order,
                             int* __restrict__ offsets, int* __restrict__ tlist)
{
  __shared__ int cnt[8];
  __shared__ int base[8];
  const int t = threadIdx.x;
  if (t < 8) cnt[t] = 0;
  __syncthreads();
  const int s = sel[t];
  atomicAdd(&cnt[s], 1);
  __syncthreads();
  if (t == 0){
    int a = 0;
    for (int o = 0; o < 8; ++o){ offsets[o] = a; base[o] = a; a += cnt[o]; }
    offsets[8] = a;
    int nt = 0;
    for (int o = 0; o < 8; ++o)
      for (int mb = offsets[o]; mb < offsets[o] + cnt[o]; mb += 64){
        tlist[1 + 2*nt] = o; tlist[2 + 2*nt] = mb; ++nt;
      }
    tlist[0] = nt;
  }
  __syncthreads();
  const int pos = atomicAdd(&base[s], 1);
  order[pos] = t;   // permutation within an expert is nondeterministic; outputs don't depend on it
}

extern "C" void kernel_launch(void* const* d_in, const int* in_sizes, int n_in,
                              void* d_out, int out_size, void* d_ws, size_t ws_size,
                              hipStream_t stream)
{
  (void)in_sizes; (void)n_in; (void)out_size; (void)ws_size;
  const float* state = (const float*)d_in[0];
  const float* ow1   = (const float*)d_in[1];
  const float* ob1   = (const float*)d_in[2];
  const float* ow2   = (const float*)d_in[3];
  const float* ob2   = (const float*)d_in[4];
  const float* aw1   = (const float*)d_in[5];
  const float* ab1   = (const float*)d_in[6];
  const float* awh   = (const float*)d_in[7];
  const float* abh   = (const float*)d_in[8];
  const float* awo   = (const float*)d_in[9];
  const float* abo   = (const float*)d_in[10];
  const float* tw1   = (const float*)d_in[11];
  const float* tb1   = (const float*)d_in[12];
  const float* tw2   = (const float*)d_in[13];
  const float* tb2   = (const float*)d_in[14];
  float* out = (float*)d_out;

  float* ba = (float*)d_ws;                                 // dense opt kb0
  float* bb = ba + (long long)Bsz * Hdim;                   // dense opt kb1
  float* bc = bb + (long long)Bsz * Hdim;                   // dense term kb0
  float* bd = bc + (long long)Bsz * Hdim;                   // dense term kb1
  float* qp = bd + (long long)Bsz * Hdim;                   // q partials [4][1024][64]
  unsigned short* sthi = (unsigned short*)(qp + 4ll * Bsz * Aact);  // state hi [1024][512]
  unsigned short* stlo = sthi + (long long)Bsz * Din;
  unsigned short* h1hi = stlo + (long long)Bsz * Din;       // L1 out hi/lo [1024][1024]
  unsigned short* h1lo = h1hi + (long long)Bsz * Hdim;
  unsigned short* h2hi = h1lo + (long long)Bsz * Hdim;      // L2 out hi/lo [1024][1024]
  unsigned short* h2lo = h2hi + (long long)Bsz * Hdim;
  int* sel     = (int*)(h2lo + (long long)Bsz * Hdim);
  int* order   = sel + Bsz;
  int* offsets = order + Bsz;
  int* tlist   = offsets + 9;           // [ntiles | (expert,mbase) * MAXT]

  // 1. state -> hi/lo bf16
  convert_state<<<dim3(512), 256, 0, stream>>>(state, sthi, stlo);
  // 2. dense pair raw sums, global split-K x2: opt kb0->ba kb1->bb; term kb0->bc kb1->bd
  mfma_gemm<true, false, false, true><<<dim3(16, 16, 4), 256, 0, stream>>>(
      sthi, stlo, Din, ow1, tw1, 0, nullptr, nullptr, 0, ba, bc, bb, bd, nullptr, nullptr,
      Hdim, Din, nullptr, nullptr, nullptr);
  // 3. heads (fold dense sums+bias+relu): opt softmax/argmax, gumbel sel, termination
  head_kernel<<<dim3(Bsz), 256, 0, stream>>>(
      ba, bb, bc, bd, ob1, tb1, ow2, ob2, tw2, tb2, out, sel);
  // 4. bucket samples by expert + tile list
  route_kernel<<<dim3(1), 1024, 0, stream>>>(sel, order, offsets, tlist);
  // 5. expert L1 (gather state rows): h1hi/lo[r] = split(relu(state[order[r]] @ aw1[o] + ab1[o]))
  mfma_gemm<false, true, true, false><<<dim3(MAXT, 16), 256, 0, stream>>>(
      sthi, stlo, Din, aw1, nullptr, (long long)Din*Hdim, ab1, nullptr, Hdim,
      nullptr, nullptr, nullptr, nullptr, h1hi, h1lo, Hdim, Din, order, offsets, tlist);
  // 6. expert L2: h2hi/lo[r] = split(relu(h1[r] @ awh[o,0] + abh[o,0]))
  mfma_gemm<false, false, true, false><<<dim3(MAXT, 16), 256, 0, stream>>>(
      h1hi, h1lo, Hdim, awh, nullptr, (long long)Hdim*Hdim, abh, nullptr, Hdim,
      nullptr, nullptr, nullptr, nullptr, h2hi, h2lo, Hdim, Hdim, nullptr, offsets, tlist);
  // 7. q partials: qp[kb] = h2 @ awo[o] (chunk kb of K)   [MFMA, split-K x4]
  q_mfma<<<dim3(MAXT, 4), 256, 0, stream>>>(h2hi, h2lo, awo, qp, offsets, tlist);
  // 8. action head: q = sum(qp)+abo, softmax, argmax
  act_kernel<<<dim3(Bsz), 64, 0, stream>>>(qp, abo, order, offsets, out);
}

// Round 27
// 101.899 us; speedup vs baseline: 1.8184x; 1.0476x over previous
//
#include <hip/hip_runtime.h>
#include <math.h>

#define Bsz 1024
#define Din 512
#define Hdim 1024
#define Aact 64
#define MAXT 23   // max row-tiles across experts: 7 partial + 16
#define NXCD 8

// out layout (float32): option_probs[1024*8] | action_probs[1024*64] | term[1024] | opt_argmax[1024] | sel_action[1024]
#define OFF_ACT   8192
#define OFF_TERM  73728
#define OFF_OARG  74752
#define OFF_SACT  75776

typedef __attribute__((ext_vector_type(8))) short bf16x8;
typedef __attribute__((ext_vector_type(4))) float f32x4;

// ---------------- threefry2x32-20, key (0,42), partitionable XOR-fold (verified R3-R26) ----------------
__device__ __forceinline__ unsigned rotl32(unsigned x, int d){ return (x << d) | (x >> (32 - d)); }

__device__ __forceinline__ void threefry_042(unsigned& x0, unsigned& x1){
  const unsigned ks0 = 0u, ks1 = 42u, ks2 = 0x1BD11BDAu ^ 0u ^ 42u;
  x0 += ks0; x1 += ks1;
#define TFR(r) { x0 += x1; x1 = rotl32(x1, r); x1 ^= x0; }
  TFR(13) TFR(15) TFR(26) TFR(6)  x0 += ks1; x1 += ks2 + 1u;
  TFR(17) TFR(29) TFR(16) TFR(24) x0 += ks2; x1 += ks0 + 2u;
  TFR(13) TFR(15) TFR(26) TFR(6)  x0 += ks0; x1 += ks1 + 3u;
  TFR(17) TFR(29) TFR(16) TFR(24) x0 += ks1; x1 += ks2 + 4u;
  TFR(13) TFR(15) TFR(26) TFR(6)  x0 += ks2; x1 += ks0 + 5u;
#undef TFR
}

__device__ __forceinline__ float gumbel_at(int idx){
  unsigned x0 = 0u, x1 = (unsigned)idx;
  threefry_042(x0, x1);
  unsigned bits = x0 ^ x1;
  float f = __uint_as_float((bits >> 9) | 0x3F800000u) - 1.0f;
  float u = fmaxf(f, 1.1754944e-38f);
  return -logf(-logf(u));
}

// ---------------- bf16 hi/lo split helpers (RNE) ----------------
__device__ __forceinline__ unsigned short bf16_rne(float x){
  unsigned u = __float_as_uint(x);
  return (unsigned short)((u + 0x7FFFu + ((u >> 16) & 1u)) >> 16);
}
__device__ __forceinline__ float bf16_tof(unsigned short h){
  return __uint_as_float(((unsigned)h) << 16);
}

// ---------------- state -> hi/lo bf16 (row-major, same indexing) ----------------
__global__ __launch_bounds__(256)
void convert_state(const float* __restrict__ st, unsigned short* __restrict__ hi,
                   unsigned short* __restrict__ lo)
{
  const int i = (blockIdx.x * 256 + threadIdx.x) * 4;
  float4 v = *(const float4*)(st + i);
  ushort4 h, l;
  h.x = bf16_rne(v.x); l.x = bf16_rne(v.x - bf16_tof(h.x));
  h.y = bf16_rne(v.y); l.y = bf16_rne(v.y - bf16_tof(h.y));
  h.z = bf16_rne(v.z); l.z = bf16_rne(v.z - bf16_tof(h.z));
  h.w = bf16_rne(v.w); l.w = bf16_rne(v.w - bf16_tof(h.w));
  *(ushort4*)(hi + i) = h;
  *(ushort4*)(lo + i) = l;
}

// ---------------- bf16x3 MFMA GEMM: 64x64 tile, 4 waves = 32x32 quadrants, k-step 64 ----------------
// R27 = R23 VERBATIM (proven best, 101.5us). R24 dbuf / R25 T14 / R26 dense-splitK all falsified.
// a*b ~= ahi*bhi + ahi*blo + alo*bhi (fp32 MFMA accum); error class == fp32 split-K reorder.
// mfma_f32_16x16x32_bf16 layouts: A row=l&15,k=(l>>4)*8+e; B col=l&15; D col=l&15,row=(l>>4)*4+r.
template<bool DENSE, bool GATHER, bool HILOOUT>
__global__ __launch_bounds__(256)
void mfma_gemm(const unsigned short* __restrict__ Ahi, const unsigned short* __restrict__ Alo,
               int lda,
               const float* __restrict__ W0, const float* __restrict__ W1, long long wstride,
               const float* __restrict__ b0, const float* __restrict__ b1, int bstride,
               float* __restrict__ C0, float* __restrict__ C1,
               unsigned short* __restrict__ Chi, unsigned short* __restrict__ Clo,
               int N, int K,
               const int* __restrict__ order, const int* __restrict__ offsets,
               const int* __restrict__ tlist)
{
  const float* W; const float* bias; float* C;
  int mbase, r1, n0;
  if (DENSE){
    const int bid = (int)(blockIdx.x + 16u*blockIdx.y + 256u*blockIdx.z);
    const int wf = (bid & 7) * 64 + (bid >> 3);     // bijective XCD swizzle
    const int ny = wf & 15, mx = (wf >> 4) & 15, z = wf >> 8;
    mbase = mx * 64; r1 = Bsz; n0 = ny * 64;
    W = z ? W1 : W0; bias = z ? b1 : b0; C = z ? C1 : C0;
  } else {
    const int bid = (int)(blockIdx.x + gridDim.x * blockIdx.y);
    const int wf = (bid % NXCD) * ((MAXT * 16) / NXCD) + bid / NXCD;
    const int i = wf >> 4;
    if (i >= tlist[0]) return;
    const int o = tlist[1 + 2*i];
    mbase = tlist[2 + 2*i];
    r1 = offsets[o + 1];
    n0 = (wf & 15) * 64;
    W = W0 + (long long)o * wstride; bias = b0 + o * bstride; C = C0;
  }

  __shared__ unsigned short sAh[4096], sAl[4096], sBh[4096], sBl[4096];   // 32KB, k-step 64

  const int tid = threadIdx.x;
  const int wv = tid >> 6, lane = tid & 63;

  const int ar = tid & 63, akb = tid >> 6;
  int grow = mbase + ar;
  int arow = grow < r1 ? grow : mbase;
  if (GATHER) arow = order[arow];
  const unsigned short* pAh = Ahi + (long long)arow * lda;
  const unsigned short* pAl = Alo + (long long)arow * lda;

  const int qr = (wv >> 1) * 32, qc = (wv & 1) * 32;

  f32x4 acc[2][2];
#pragma unroll
  for (int a = 0; a < 2; a++)
#pragma unroll
    for (int b = 0; b < 2; b++) acc[a][b] = (f32x4){0.f, 0.f, 0.f, 0.f};

  for (int kt = 0; kt < K; kt += 64){
#pragma unroll
    for (int h = 0; h < 2; h++){
      const int kbl = akb + h*4;
      *(float4*)(sAh + kbl*512 + ar*8) = *(const float4*)(pAh + kt + kbl*8);
      *(float4*)(sAl + kbl*512 + ar*8) = *(const float4*)(pAl + kt + kbl*8);
    }
#pragma unroll
    for (int rp = 0; rp < 8; rp++){
      const int kl = wv * 16 + rp * 2;
      const int kbl = kl >> 3, e = kl & 7;
      const float v0 = W[(long long)(kt + kl) * N + n0 + lane];
      const float v1 = W[(long long)(kt + kl + 1) * N + n0 + lane];
      const unsigned short h0 = bf16_rne(v0), h1 = bf16_rne(v1);
      const unsigned short l0 = bf16_rne(v0 - bf16_tof(h0)), l1 = bf16_rne(v1 - bf16_tof(h1));
      *(unsigned*)(sBh + kbl*512 + lane*8 + e) = ((unsigned)h1 << 16) | h0;
      *(unsigned*)(sBl + kbl*512 + lane*8 + e) = ((unsigned)l1 << 16) | l0;
    }
    __syncthreads();
#pragma unroll
    for (int kg = 0; kg < 2; kg++){
      const int g = (kg*4 + (lane >> 4)) * 512, li = lane & 15;
      bf16x8 a0h = *(const bf16x8*)(sAh + g + (qr + li) * 8);
      bf16x8 a1h = *(const bf16x8*)(sAh + g + (qr + 16 + li) * 8);
      bf16x8 a0l = *(const bf16x8*)(sAl + g + (qr + li) * 8);
      bf16x8 a1l = *(const bf16x8*)(sAl + g + (qr + 16 + li) * 8);
      bf16x8 b0h = *(const bf16x8*)(sBh + g + (qc + li) * 8);
      bf16x8 b1h = *(const bf16x8*)(sBh + g + (qc + 16 + li) * 8);
      bf16x8 b0l = *(const bf16x8*)(sBl + g + (qc + li) * 8);
      bf16x8 b1l = *(const bf16x8*)(sBl + g + (qc + 16 + li) * 8);
      acc[0][0] = __builtin_amdgcn_mfma_f32_16x16x32_bf16(a0h, b0h, acc[0][0], 0, 0, 0);
      acc[0][1] = __builtin_amdgcn_mfma_f32_16x16x32_bf16(a0h, b1h, acc[0][1], 0, 0, 0);
      acc[1][0] = __builtin_amdgcn_mfma_f32_16x16x32_bf16(a1h, b0h, acc[1][0], 0, 0, 0);
      acc[1][1] = __builtin_amdgcn_mfma_f32_16x16x32_bf16(a1h, b1h, acc[1][1], 0, 0, 0);
      acc[0][0] = __builtin_amdgcn_mfma_f32_16x16x32_bf16(a0h, b0l, acc[0][0], 0, 0, 0);
      acc[0][1] = __builtin_amdgcn_mfma_f32_16x16x32_bf16(a0h, b1l, acc[0][1], 0, 0, 0);
      acc[1][0] = __builtin_amdgcn_mfma_f32_16x16x32_bf16(a1h, b0l, acc[1][0], 0, 0, 0);
      acc[1][1] = __builtin_amdgcn_mfma_f32_16x16x32_bf16(a1h, b1l, acc[1][1], 0, 0, 0);
      acc[0][0] = __builtin_amdgcn_mfma_f32_16x16x32_bf16(a0l, b0h, acc[0][0], 0, 0, 0);
      acc[0][1] = __builtin_amdgcn_mfma_f32_16x16x32_bf16(a0l, b1h, acc[0][1], 0, 0, 0);
      acc[1][0] = __builtin_amdgcn_mfma_f32_16x16x32_bf16(a1l, b0h, acc[1][0], 0, 0, 0);
      acc[1][1] = __builtin_amdgcn_mfma_f32_16x16x32_bf16(a1l, b1h, acc[1][1], 0, 0, 0);
    }
    __syncthreads();
  }

#pragma unroll
  for (int rb = 0; rb < 2; rb++)
#pragma unroll
    for (int cb = 0; cb < 2; cb++){
      const int col = n0 + qc + cb*16 + (lane & 15);
      const float bv = bias[col];
#pragma unroll
      for (int r = 0; r < 4; r++){
        const int row = mbase + qr + rb*16 + (lane >> 4)*4 + r;
        if (row < r1){
          const float v = fmaxf(acc[rb][cb][r] + bv, 0.f);
          if (HILOOUT){
            const unsigned short h = bf16_rne(v);
            Chi[(long long)row * N + col] = h;
            Clo[(long long)row * N + col] = bf16_rne(v - bf16_tof(h));
          } else {
            C[(long long)row * N + col] = v;
          }
        }
      }
    }
}

// ---------------- q = h2 @ awo[o] (raw, no bias): grouped bf16x3 MFMA, N=64, global split-K x4 ----
__global__ __launch_bounds__(256)
void q_mfma(const unsigned short* __restrict__ Ahi, const unsigned short* __restrict__ Alo,
            const float* __restrict__ awo,
            float* __restrict__ qp,
            const int* __restrict__ offsets, const int* __restrict__ tlist)
{
  const int i = blockIdx.x;
  if (i >= tlist[0]) return;
  const int o = tlist[1 + 2*i];
  const int mbase = tlist[2 + 2*i];
  const int r1 = offsets[o + 1];
  const int kb = blockIdx.y;
  const float* W = awo + (long long)o * Hdim * Aact;

  __shared__ unsigned short sAh[4096], sAl[4096], sBh[4096], sBl[4096];

  const int tid = threadIdx.x;
  const int wv = tid >> 6, lane = tid & 63;
  const int ar = tid & 63, akb = tid >> 6;
  int grow = mbase + ar;
  int arow = grow < r1 ? grow : mbase;
  const unsigned short* pAh = Ahi + (long long)arow * Hdim;
  const unsigned short* pAl = Alo + (long long)arow * Hdim;

  const int qr = (wv >> 1) * 32, qc = (wv & 1) * 32;

  f32x4 acc[2][2];
#pragma unroll
  for (int a = 0; a < 2; a++)
#pragma unroll
    for (int b = 0; b < 2; b++) acc[a][b] = (f32x4){0.f, 0.f, 0.f, 0.f};

  const int kbeg = kb * 256, kend = kbeg + 256;
  for (int kt = kbeg; kt < kend; kt += 64){
#pragma unroll
    for (int h = 0; h < 2; h++){
      const int kbl = akb + h*4;
      *(float4*)(sAh + kbl*512 + ar*8) = *(const float4*)(pAh + kt + kbl*8);
      *(float4*)(sAl + kbl*512 + ar*8) = *(const float4*)(pAl + kt + kbl*8);
    }
#pragma unroll
    for (int rp = 0; rp < 8; rp++){
      const int kl = wv * 16 + rp * 2;
      const int kbl = kl >> 3, e = kl & 7;
      const float v0 = W[(kt + kl) * Aact + lane];
      const float v1 = W[(kt + kl + 1) * Aact + lane];
      const unsigned short h0 = bf16_rne(v0), h1 = bf16_rne(v1);
      const unsigned short l0 = bf16_rne(v0 - bf16_tof(h0)), l1 = bf16_rne(v1 - bf16_tof(h1));
      *(unsigned*)(sBh + kbl*512 + lane*8 + e) = ((unsigned)h1 << 16) | h0;
      *(unsigned*)(sBl + kbl*512 + lane*8 + e) = ((unsigned)l1 << 16) | l0;
    }
    __syncthreads();
#pragma unroll
    for (int kg = 0; kg < 2; kg++){
      const int g = (kg*4 + (lane >> 4)) * 512, li = lane & 15;
      bf16x8 a0h = *(const bf16x8*)(sAh + g + (qr + li) * 8);
      bf16x8 a1h = *(const bf16x8*)(sAh + g + (qr + 16 + li) * 8);
      bf16x8 a0l = *(const bf16x8*)(sAl + g + (qr + li) * 8);
      bf16x8 a1l = *(const bf16x8*)(sAl + g + (qr + 16 + li) * 8);
      bf16x8 b0h = *(const bf16x8*)(sBh + g + (qc + li) * 8);
      bf16x8 b1h = *(const bf16x8*)(sBh + g + (qc + 16 + li) * 8);
      bf16x8 b0l = *(const bf16x8*)(sBl + g + (qc + li) * 8);
      bf16x8 b1l = *(const bf16x8*)(sBl + g + (qc + 16 + li) * 8);
      acc[0][0] = __builtin_amdgcn_mfma_f32_16x16x32_bf16(a0h, b0h, acc[0][0], 0, 0, 0);
      acc[0][1] = __builtin_amdgcn_mfma_f32_16x16x32_bf16(a0h, b1h, acc[0][1], 0, 0, 0);
      acc[1][0] = __builtin_amdgcn_mfma_f32_16x16x32_bf16(a1h, b0h, acc[1][0], 0, 0, 0);
      acc[1][1] = __builtin_amdgcn_mfma_f32_16x16x32_bf16(a1h, b1h, acc[1][1], 0, 0, 0);
      acc[0][0] = __builtin_amdgcn_mfma_f32_16x16x32_bf16(a0h, b0l, acc[0][0], 0, 0, 0);
      acc[0][1] = __builtin_amdgcn_mfma_f32_16x16x32_bf16(a0h, b1l, acc[0][1], 0, 0, 0);
      acc[1][0] = __builtin_amdgcn_mfma_f32_16x16x32_bf16(a1h, b0l, acc[1][0], 0, 0, 0);
      acc[1][1] = __builtin_amdgcn_mfma_f32_16x16x32_bf16(a1h, b1l, acc[1][1], 0, 0, 0);
      acc[0][0] = __builtin_amdgcn_mfma_f32_16x16x32_bf16(a0l, b0h, acc[0][0], 0, 0, 0);
      acc[0][1] = __builtin_amdgcn_mfma_f32_16x16x32_bf16(a0l, b1h, acc[0][1], 0, 0, 0);
      acc[1][0] = __builtin_amdgcn_mfma_f32_16x16x32_bf16(a1l, b0h, acc[1][0], 0, 0, 0);
      acc[1][1] = __builtin_amdgcn_mfma_f32_16x16x32_bf16(a1l, b1h, acc[1][1], 0, 0, 0);
    }
    __syncthreads();
  }

#pragma unroll
  for (int rb = 0; rb < 2; rb++)
#pragma unroll
    for (int cb = 0; cb < 2; cb++){
      const int col = qc + cb*16 + (lane & 15);
#pragma unroll
      for (int r = 0; r < 4; r++){
        const int row = mbase + qr + rb*16 + (lane >> 4)*4 + r;
        if (row < r1)
          qp[((long long)kb * Bsz + row) * Aact + col] = acc[rb][cb][r];
      }
    }
}

// ---------------- per-row action head: q = sum(qp) + abo[o], softmax, argmax (1 wave/row) ----------
__global__ __launch_bounds__(64)
void act_kernel(const float* __restrict__ qp, const float* __restrict__ abo,
                const int* __restrict__ order, const int* __restrict__ offsets,
                float* __restrict__ out)
{
  const int r = blockIdx.x;
  int o = 0;
#pragma unroll
  for (int i = 1; i < 8; ++i) if (offsets[i] <= r) o = i;
  const int a = threadIdx.x;
  const long long idx = (long long)r * Aact + a;
  float q = qp[idx] + qp[(long long)Bsz*Aact + idx] + qp[2ll*Bsz*Aact + idx]
          + qp[3ll*Bsz*Aact + idx] + abo[o * Aact + a];
  float m = q;
#pragma unroll
  for (int off = 32; off; off >>= 1) m = fmaxf(m, __shfl_xor(m, off));
  float e = expf(q - m);
  float s = e;
#pragma unroll
  for (int off = 32; off; off >>= 1) s += __shfl_xor(s, off);
  const int b = order[r];
  out[OFF_ACT + b * Aact + a] = e / s;
  unsigned long long msk = __ballot(q == m);
  if (a == 0) out[OFF_SACT + b] = (float)__builtin_ctzll(msk);
}

// ---------------- per-row head: opt logits + softmax + argmax + gumbel sel + termination ----------------
__global__ __launch_bounds__(256)
void head_kernel(const float* __restrict__ h1, const float* __restrict__ th,
                 const float* __restrict__ ow2, const float* __restrict__ ob2,
                 const float* __restrict__ tw2, const float* __restrict__ tb2,
                 float* __restrict__ out, int* __restrict__ sel)
{
  const int b = blockIdx.x;
  const int t = threadIdx.x;
  const float* hrow = h1 + b * Hdim;
  const float* trow = th + b * Hdim;

  float acc[8] = {}; float accT = 0.f;
  for (int k = t; k < Hdim; k += 256){
    float hv = hrow[k];
    const float* w = ow2 + k * 8;
#pragma unroll
    for (int o2 = 0; o2 < 8; ++o2) acc[o2] += hv * w[o2];
    accT += trow[k] * tw2[k];
  }
#pragma unroll
  for (int o2 = 0; o2 < 8; ++o2)
    for (int off = 32; off; off >>= 1) acc[o2] += __shfl_down(acc[o2], off);
  for (int off = 32; off; off >>= 1) accT += __shfl_down(accT, off);

  __shared__ float wred[4][9];
  __shared__ float logits[8];
  __shared__ float gum[8];
  const int wave = t >> 6, lane = t & 63;
  if (lane == 0){
#pragma unroll
    for (int o2 = 0; o2 < 8; ++o2) wred[wave][o2] = acc[o2];
    wred[wave][8] = accT;
  }
  __syncthreads();
  if (t < 9){
    float s = wred[0][t] + wred[1][t] + wred[2][t] + wred[3][t];
    if (t < 8) logits[t] = s + ob2[t];
    else       out[OFF_TERM + b] = 1.f / (1.f + expf(-(s + tb2[0])));
  }
  __syncthreads();
  if (t < 8) gum[t] = logits[t] + gumbel_at(b * 8 + t);
  __syncthreads();
  if (t == 0){
    float m = logits[0]; int am = 0;
#pragma unroll
    for (int o2 = 1; o2 < 8; ++o2) if (logits[o2] > m){ m = logits[o2]; am = o2; }
    float p[8]; float s = 0.f;
#pragma unroll
    for (int o2 = 0; o2 < 8; ++o2){ p[o2] = expf(logits[o2] - m); s += p[o2]; }
    float inv = 1.f / s;
#pragma unroll
    for (int o2 = 0; o2 < 8; ++o2) out[b * 8 + o2] = p[o2] * inv;
    out[OFF_OARG + b] = (float)am;
    float gm = gum[0]; int gs = 0;
#pragma unroll
    for (int o2 = 1; o2 < 8; ++o2) if (gum[o2] > gm){ gm = gum[o2]; gs = o2; }
    sel[b] = gs;
  }
}

// ---------------- routing: bucket samples by expert + emit row-tile list ----------------
__global__ void route_kernel(const int* __restrict__ sel, int* __restrict__ order,
                             int* __restrict__ offsets, int* __restrict__ tlist)
{
  __shared__ int cnt[8];
  __shared__ int base[8];
  const int t = threadIdx.x;
  if (t < 8) cnt[t] = 0;
  __syncthreads();
  const int s = sel[t];
  atomicAdd(&cnt[s], 1);
  __syncthreads();
  if (t == 0){
    int a = 0;
    for (int o = 0; o < 8; ++o){ offsets[o] = a; base[o] = a; a += cnt[o]; }
    offsets[8] = a;
    int nt = 0;
    for (int o = 0; o < 8; ++o)
      for (int mb = offsets[o]; mb < offsets[o] + cnt[o]; mb += 64){
        tlist[1 + 2*nt] = o; tlist[2 + 2*nt] = mb; ++nt;
      }
    tlist[0] = nt;
  }
  __syncthreads();
  const int pos = atomicAdd(&base[s], 1);
  order[pos] = t;   // permutation within an expert is nondeterministic; outputs don't depend on it
}

extern "C" void kernel_launch(void* const* d_in, const int* in_sizes, int n_in,
                              void* d_out, int out_size, void* d_ws, size_t ws_size,
                              hipStream_t stream)
{
  (void)in_sizes; (void)n_in; (void)out_size; (void)ws_size;
  const float* state = (const float*)d_in[0];
  const float* ow1   = (const float*)d_in[1];
  const float* ob1   = (const float*)d_in[2];
  const float* ow2   = (const float*)d_in[3];
  const float* ob2   = (const float*)d_in[4];
  const float* aw1   = (const float*)d_in[5];
  const float* ab1   = (const float*)d_in[6];
  const float* awh   = (const float*)d_in[7];
  const float* abh   = (const float*)d_in[8];
  const float* awo   = (const float*)d_in[9];
  const float* abo   = (const float*)d_in[10];
  const float* tw1   = (const float*)d_in[11];
  const float* tb1   = (const float*)d_in[12];
  const float* tw2   = (const float*)d_in[13];
  const float* tb2   = (const float*)d_in[14];
  float* out = (float*)d_out;

  float* h1 = (float*)d_ws;                                 // dense opt hidden (fp32)
  float* h2 = h1 + (long long)Bsz * Hdim;                   // dense term hidden (fp32)
  float* qp = h2 + (long long)Bsz * Hdim;                   // q partials [4][1024][64]
  unsigned short* sthi = (unsigned short*)(qp + 4ll * Bsz * Aact);  // state hi [1024][512]
  unsigned short* stlo = sthi + (long long)Bsz * Din;
  unsigned short* h1hi = stlo + (long long)Bsz * Din;       // L1 out hi/lo [1024][1024]
  unsigned short* h1lo = h1hi + (long long)Bsz * Hdim;
  unsigned short* h2hi = h1lo + (long long)Bsz * Hdim;      // L2 out hi/lo [1024][1024]
  unsigned short* h2lo = h2hi + (long long)Bsz * Hdim;
  int* sel     = (int*)(h2lo + (long long)Bsz * Hdim);
  int* order   = sel + Bsz;
  int* offsets = order + Bsz;
  int* tlist   = offsets + 9;           // [ntiles | (expert,mbase) * MAXT]

  // 1. state -> hi/lo bf16
  convert_state<<<dim3(512), 256, 0, stream>>>(state, sthi, stlo);
  // 2. dense pair: h1 = relu(st @ ow1 + ob1), h2 = relu(st @ tw1 + tb1)
  mfma_gemm<true, false, false><<<dim3(16, 16, 2), 256, 0, stream>>>(
      sthi, stlo, Din, ow1, tw1, 0, ob1, tb1, 0, h1, h2, nullptr, nullptr,
      Hdim, Din, nullptr, nullptr, nullptr);
  // 3. heads: opt softmax/argmax, gumbel categorical sel, termination sigmoid
  head_kernel<<<dim3(Bsz), 256, 0, stream>>>(h1, h2, ow2, ob2, tw2, tb2, out, sel);
  // 4. bucket samples by expert + tile list
  route_kernel<<<dim3(1), 1024, 0, stream>>>(sel, order, offsets, tlist);
  // 5. expert L1 (gather state rows): h1hi/lo[r] = split(relu(state[order[r]] @ aw1[o] + ab1[o]))
  mfma_gemm<false, true, true><<<dim3(MAXT, 16), 256, 0, stream>>>(
      sthi, stlo, Din, aw1, nullptr, (long long)Din*Hdim, ab1, nullptr, Hdim,
      nullptr, nullptr, h1hi, h1lo, Hdim, Din, order, offsets, tlist);
  // 6. expert L2: h2hi/lo[r] = split(relu(h1[r] @ awh[o,0] + abh[o,0]))
  mfma_gemm<false, false, true><<<dim3(MAXT, 16), 256, 0, stream>>>(
      h1hi, h1lo, Hdim, awh, nullptr, (long long)Hdim*Hdim, abh, nullptr, Hdim,
      nullptr, nullptr, h2hi, h2lo, Hdim, Hdim, nullptr, offsets, tlist);
  // 7. q partials: qp[kb] = h2 @ awo[o] (chunk kb of K)   [MFMA, split-K x4]
  q_mfma<<<dim3(MAXT, 4), 256, 0, stream>>>(h2hi, h2lo, awo, qp, offsets, tlist);
  // 8. action head: q = sum(qp)+abo, softmax, argmax
  act_kernel<<<dim3(Bsz), 64, 0, stream>>>(qp, abo, order, offsets, out);
}

// Round 28
// 98.552 us; speedup vs baseline: 1.8802x; 1.0340x over previous
//
#include <hip/hip_runtime.h>
#include <math.h>

#define Bsz 1024
#define Din 512
#define Hdim 1024
#define Aact 64
#define MAXT 23   // max row-tiles across experts: 7 partial + 16
#define NXCD 8

// out layout (float32): option_probs[1024*8] | action_probs[1024*64] | term[1024] | opt_argmax[1024] | sel_action[1024]
#define OFF_ACT   8192
#define OFF_TERM  73728
#define OFF_OARG  74752
#define OFF_SACT  75776

typedef __attribute__((ext_vector_type(8))) short bf16x8;
typedef __attribute__((ext_vector_type(4))) float f32x4;

// ---------------- threefry2x32-20, key (0,42), partitionable XOR-fold (verified R3-R27) ----------------
__device__ __forceinline__ unsigned rotl32(unsigned x, int d){ return (x << d) | (x >> (32 - d)); }

__device__ __forceinline__ void threefry_042(unsigned& x0, unsigned& x1){
  const unsigned ks0 = 0u, ks1 = 42u, ks2 = 0x1BD11BDAu ^ 0u ^ 42u;
  x0 += ks0; x1 += ks1;
#define TFR(r) { x0 += x1; x1 = rotl32(x1, r); x1 ^= x0; }
  TFR(13) TFR(15) TFR(26) TFR(6)  x0 += ks1; x1 += ks2 + 1u;
  TFR(17) TFR(29) TFR(16) TFR(24) x0 += ks2; x1 += ks0 + 2u;
  TFR(13) TFR(15) TFR(26) TFR(6)  x0 += ks0; x1 += ks1 + 3u;
  TFR(17) TFR(29) TFR(16) TFR(24) x0 += ks1; x1 += ks2 + 4u;
  TFR(13) TFR(15) TFR(26) TFR(6)  x0 += ks2; x1 += ks0 + 5u;
#undef TFR
}

__device__ __forceinline__ float gumbel_at(int idx){
  unsigned x0 = 0u, x1 = (unsigned)idx;
  threefry_042(x0, x1);
  unsigned bits = x0 ^ x1;
  float f = __uint_as_float((bits >> 9) | 0x3F800000u) - 1.0f;
  float u = fmaxf(f, 1.1754944e-38f);
  return -logf(-logf(u));
}

// ---------------- bf16 hi/lo split helpers (RNE) ----------------
__device__ __forceinline__ unsigned short bf16_rne(float x){
  unsigned u = __float_as_uint(x);
  return (unsigned short)((u + 0x7FFFu + ((u >> 16) & 1u)) >> 16);
}
__device__ __forceinline__ float bf16_tof(unsigned short h){
  return __uint_as_float(((unsigned)h) << 16);
}

// ---------------- bf16x3 MFMA GEMM: 64x64 tile, 4 waves = 32x32 quadrants, k-step 64 ----------------
// R28 = R23 (proven best, 101.5us) + ASPLIT: A supplied as fp32 and hi/lo-split during A-staging
// (same RNE math the B-path does) — removes the separate convert_state launch, shortening the
// 8-launch dependency chain to 7. Everything else verbatim.
// a*b ~= ahi*bhi + ahi*blo + alo*bhi (fp32 MFMA accum); error class == fp32 split-K reorder.
// mfma_f32_16x16x32_bf16 layouts: A row=l&15,k=(l>>4)*8+e; B col=l&15; D col=l&15,row=(l>>4)*4+r.
template<bool DENSE, bool GATHER, bool HILOOUT, bool ASPLIT>
__global__ __launch_bounds__(256)
void mfma_gemm(const unsigned short* __restrict__ Ahi, const unsigned short* __restrict__ Alo,
               const float* __restrict__ Af, int lda,
               const float* __restrict__ W0, const float* __restrict__ W1, long long wstride,
               const float* __restrict__ b0, const float* __restrict__ b1, int bstride,
               float* __restrict__ C0, float* __restrict__ C1,
               unsigned short* __restrict__ Chi, unsigned short* __restrict__ Clo,
               int N, int K,
               const int* __restrict__ order, const int* __restrict__ offsets,
               const int* __restrict__ tlist)
{
  const float* W; const float* bias; float* C;
  int mbase, r1, n0;
  if (DENSE){
    const int bid = (int)(blockIdx.x + 16u*blockIdx.y + 256u*blockIdx.z);
    const int wf = (bid & 7) * 64 + (bid >> 3);     // bijective XCD swizzle
    const int ny = wf & 15, mx = (wf >> 4) & 15, z = wf >> 8;
    mbase = mx * 64; r1 = Bsz; n0 = ny * 64;
    W = z ? W1 : W0; bias = z ? b1 : b0; C = z ? C1 : C0;
  } else {
    const int bid = (int)(blockIdx.x + gridDim.x * blockIdx.y);
    const int wf = (bid % NXCD) * ((MAXT * 16) / NXCD) + bid / NXCD;
    const int i = wf >> 4;
    if (i >= tlist[0]) return;
    const int o = tlist[1 + 2*i];
    mbase = tlist[2 + 2*i];
    r1 = offsets[o + 1];
    n0 = (wf & 15) * 64;
    W = W0 + (long long)o * wstride; bias = b0 + o * bstride; C = C0;
  }

  __shared__ unsigned short sAh[4096], sAl[4096], sBh[4096], sBl[4096];   // 32KB, k-step 64

  const int tid = threadIdx.x;
  const int wv = tid >> 6, lane = tid & 63;

  const int ar = tid & 63, akb = tid >> 6;
  int grow = mbase + ar;
  int arow = grow < r1 ? grow : mbase;
  if (GATHER) arow = order[arow];
  const unsigned short* pAh = ASPLIT ? nullptr : (Ahi + (long long)arow * lda);
  const unsigned short* pAl = ASPLIT ? nullptr : (Alo + (long long)arow * lda);
  const float*          pAf = ASPLIT ? (Af + (long long)arow * lda) : nullptr;

  const int qr = (wv >> 1) * 32, qc = (wv & 1) * 32;

  f32x4 acc[2][2];
#pragma unroll
  for (int a = 0; a < 2; a++)
#pragma unroll
    for (int b = 0; b < 2; b++) acc[a][b] = (f32x4){0.f, 0.f, 0.f, 0.f};

  for (int kt = 0; kt < K; kt += 64){
    // ---- stage A: fragment-order copies (bf16 b128 pass-through, or fp32 load + RNE split) ----
#pragma unroll
    for (int h = 0; h < 2; h++){
      const int kbl = akb + h*4;
      if (ASPLIT){
        const float4 v0 = *(const float4*)(pAf + kt + kbl*8);
        const float4 v1 = *(const float4*)(pAf + kt + kbl*8 + 4);
        const float vs[8] = {v0.x, v0.y, v0.z, v0.w, v1.x, v1.y, v1.z, v1.w};
        ushort4 ph0, ph1, pl0, pl1;
        unsigned short hh[8], ll[8];
#pragma unroll
        for (int e = 0; e < 8; e++){
          hh[e] = bf16_rne(vs[e]);
          ll[e] = bf16_rne(vs[e] - bf16_tof(hh[e]));
        }
        ph0 = make_ushort4(hh[0], hh[1], hh[2], hh[3]);
        ph1 = make_ushort4(hh[4], hh[5], hh[6], hh[7]);
        pl0 = make_ushort4(ll[0], ll[1], ll[2], ll[3]);
        pl1 = make_ushort4(ll[4], ll[5], ll[6], ll[7]);
        *(ushort4*)(sAh + kbl*512 + ar*8)     = ph0;
        *(ushort4*)(sAh + kbl*512 + ar*8 + 4) = ph1;
        *(ushort4*)(sAl + kbl*512 + ar*8)     = pl0;
        *(ushort4*)(sAl + kbl*512 + ar*8 + 4) = pl1;
      } else {
        *(float4*)(sAh + kbl*512 + ar*8) = *(const float4*)(pAh + kt + kbl*8);
        *(float4*)(sAl + kbl*512 + ar*8) = *(const float4*)(pAl + kt + kbl*8);
      }
    }
    // ---- stage B: wave wv covers k-rows wv*16..+15 in e-pairs; u32 paired writes ----
#pragma unroll
    for (int rp = 0; rp < 8; rp++){
      const int kl = wv * 16 + rp * 2;
      const int kbl = kl >> 3, e = kl & 7;
      const float v0 = W[(long long)(kt + kl) * N + n0 + lane];
      const float v1 = W[(long long)(kt + kl + 1) * N + n0 + lane];
      const unsigned short h0 = bf16_rne(v0), h1 = bf16_rne(v1);
      const unsigned short l0 = bf16_rne(v0 - bf16_tof(h0)), l1 = bf16_rne(v1 - bf16_tof(h1));
      *(unsigned*)(sBh + kbl*512 + lane*8 + e) = ((unsigned)h1 << 16) | h0;
      *(unsigned*)(sBl + kbl*512 + lane*8 + e) = ((unsigned)l1 << 16) | l0;
    }
    __syncthreads();
#pragma unroll
    for (int kg = 0; kg < 2; kg++){
      const int g = (kg*4 + (lane >> 4)) * 512, li = lane & 15;
      bf16x8 a0h = *(const bf16x8*)(sAh + g + (qr + li) * 8);
      bf16x8 a1h = *(const bf16x8*)(sAh + g + (qr + 16 + li) * 8);
      bf16x8 a0l = *(const bf16x8*)(sAl + g + (qr + li) * 8);
      bf16x8 a1l = *(const bf16x8*)(sAl + g + (qr + 16 + li) * 8);
      bf16x8 b0h = *(const bf16x8*)(sBh + g + (qc + li) * 8);
      bf16x8 b1h = *(const bf16x8*)(sBh + g + (qc + 16 + li) * 8);
      bf16x8 b0l = *(const bf16x8*)(sBl + g + (qc + li) * 8);
      bf16x8 b1l = *(const bf16x8*)(sBl + g + (qc + 16 + li) * 8);
      acc[0][0] = __builtin_amdgcn_mfma_f32_16x16x32_bf16(a0h, b0h, acc[0][0], 0, 0, 0);
      acc[0][1] = __builtin_amdgcn_mfma_f32_16x16x32_bf16(a0h, b1h, acc[0][1], 0, 0, 0);
      acc[1][0] = __builtin_amdgcn_mfma_f32_16x16x32_bf16(a1h, b0h, acc[1][0], 0, 0, 0);
      acc[1][1] = __builtin_amdgcn_mfma_f32_16x16x32_bf16(a1h, b1h, acc[1][1], 0, 0, 0);
      acc[0][0] = __builtin_amdgcn_mfma_f32_16x16x32_bf16(a0h, b0l, acc[0][0], 0, 0, 0);
      acc[0][1] = __builtin_amdgcn_mfma_f32_16x16x32_bf16(a0h, b1l, acc[0][1], 0, 0, 0);
      acc[1][0] = __builtin_amdgcn_mfma_f32_16x16x32_bf16(a1h, b0l, acc[1][0], 0, 0, 0);
      acc[1][1] = __builtin_amdgcn_mfma_f32_16x16x32_bf16(a1h, b1l, acc[1][1], 0, 0, 0);
      acc[0][0] = __builtin_amdgcn_mfma_f32_16x16x32_bf16(a0l, b0h, acc[0][0], 0, 0, 0);
      acc[0][1] = __builtin_amdgcn_mfma_f32_16x16x32_bf16(a0l, b1h, acc[0][1], 0, 0, 0);
      acc[1][0] = __builtin_amdgcn_mfma_f32_16x16x32_bf16(a1l, b0h, acc[1][0], 0, 0, 0);
      acc[1][1] = __builtin_amdgcn_mfma_f32_16x16x32_bf16(a1l, b1h, acc[1][1], 0, 0, 0);
    }
    __syncthreads();
  }

#pragma unroll
  for (int rb = 0; rb < 2; rb++)
#pragma unroll
    for (int cb = 0; cb < 2; cb++){
      const int col = n0 + qc + cb*16 + (lane & 15);
      const float bv = bias[col];
#pragma unroll
      for (int r = 0; r < 4; r++){
        const int row = mbase + qr + rb*16 + (lane >> 4)*4 + r;
        if (row < r1){
          const float v = fmaxf(acc[rb][cb][r] + bv, 0.f);
          if (HILOOUT){
            const unsigned short h = bf16_rne(v);
            Chi[(long long)row * N + col] = h;
            Clo[(long long)row * N + col] = bf16_rne(v - bf16_tof(h));
          } else {
            C[(long long)row * N + col] = v;
          }
        }
      }
    }
}

// ---------------- q = h2 @ awo[o] (raw, no bias): grouped bf16x3 MFMA, N=64, global split-K x4 ----
__global__ __launch_bounds__(256)
void q_mfma(const unsigned short* __restrict__ Ahi, const unsigned short* __restrict__ Alo,
            const float* __restrict__ awo,
            float* __restrict__ qp,
            const int* __restrict__ offsets, const int* __restrict__ tlist)
{
  const int i = blockIdx.x;
  if (i >= tlist[0]) return;
  const int o = tlist[1 + 2*i];
  const int mbase = tlist[2 + 2*i];
  const int r1 = offsets[o + 1];
  const int kb = blockIdx.y;
  const float* W = awo + (long long)o * Hdim * Aact;

  __shared__ unsigned short sAh[4096], sAl[4096], sBh[4096], sBl[4096];

  const int tid = threadIdx.x;
  const int wv = tid >> 6, lane = tid & 63;
  const int ar = tid & 63, akb = tid >> 6;
  int grow = mbase + ar;
  int arow = grow < r1 ? grow : mbase;
  const unsigned short* pAh = Ahi + (long long)arow * Hdim;
  const unsigned short* pAl = Alo + (long long)arow * Hdim;

  const int qr = (wv >> 1) * 32, qc = (wv & 1) * 32;

  f32x4 acc[2][2];
#pragma unroll
  for (int a = 0; a < 2; a++)
#pragma unroll
    for (int b = 0; b < 2; b++) acc[a][b] = (f32x4){0.f, 0.f, 0.f, 0.f};

  const int kbeg = kb * 256, kend = kbeg + 256;
  for (int kt = kbeg; kt < kend; kt += 64){
#pragma unroll
    for (int h = 0; h < 2; h++){
      const int kbl = akb + h*4;
      *(float4*)(sAh + kbl*512 + ar*8) = *(const float4*)(pAh + kt + kbl*8);
      *(float4*)(sAl + kbl*512 + ar*8) = *(const float4*)(pAl + kt + kbl*8);
    }
#pragma unroll
    for (int rp = 0; rp < 8; rp++){
      const int kl = wv * 16 + rp * 2;
      const int kbl = kl >> 3, e = kl & 7;
      const float v0 = W[(kt + kl) * Aact + lane];
      const float v1 = W[(kt + kl + 1) * Aact + lane];
      const unsigned short h0 = bf16_rne(v0), h1 = bf16_rne(v1);
      const unsigned short l0 = bf16_rne(v0 - bf16_tof(h0)), l1 = bf16_rne(v1 - bf16_tof(h1));
      *(unsigned*)(sBh + kbl*512 + lane*8 + e) = ((unsigned)h1 << 16) | h0;
      *(unsigned*)(sBl + kbl*512 + lane*8 + e) = ((unsigned)l1 << 16) | l0;
    }
    __syncthreads();
#pragma unroll
    for (int kg = 0; kg < 2; kg++){
      const int g = (kg*4 + (lane >> 4)) * 512, li = lane & 15;
      bf16x8 a0h = *(const bf16x8*)(sAh + g + (qr + li) * 8);
      bf16x8 a1h = *(const bf16x8*)(sAh + g + (qr + 16 + li) * 8);
      bf16x8 a0l = *(const bf16x8*)(sAl + g + (qr + li) * 8);
      bf16x8 a1l = *(const bf16x8*)(sAl + g + (qr + 16 + li) * 8);
      bf16x8 b0h = *(const bf16x8*)(sBh + g + (qc + li) * 8);
      bf16x8 b1h = *(const bf16x8*)(sBh + g + (qc + 16 + li) * 8);
      bf16x8 b0l = *(const bf16x8*)(sBl + g + (qc + li) * 8);
      bf16x8 b1l = *(const bf16x8*)(sBl + g + (qc + 16 + li) * 8);
      acc[0][0] = __builtin_amdgcn_mfma_f32_16x16x32_bf16(a0h, b0h, acc[0][0], 0, 0, 0);
      acc[0][1] = __builtin_amdgcn_mfma_f32_16x16x32_bf16(a0h, b1h, acc[0][1], 0, 0, 0);
      acc[1][0] = __builtin_amdgcn_mfma_f32_16x16x32_bf16(a1h, b0h, acc[1][0], 0, 0, 0);
      acc[1][1] = __builtin_amdgcn_mfma_f32_16x16x32_bf16(a1h, b1h, acc[1][1], 0, 0, 0);
      acc[0][0] = __builtin_amdgcn_mfma_f32_16x16x32_bf16(a0h, b0l, acc[0][0], 0, 0, 0);
      acc[0][1] = __builtin_amdgcn_mfma_f32_16x16x32_bf16(a0h, b1l, acc[0][1], 0, 0, 0);
      acc[1][0] = __builtin_amdgcn_mfma_f32_16x16x32_bf16(a1h, b0l, acc[1][0], 0, 0, 0);
      acc[1][1] = __builtin_amdgcn_mfma_f32_16x16x32_bf16(a1h, b1l, acc[1][1], 0, 0, 0);
      acc[0][0] = __builtin_amdgcn_mfma_f32_16x16x32_bf16(a0l, b0h, acc[0][0], 0, 0, 0);
      acc[0][1] = __builtin_amdgcn_mfma_f32_16x16x32_bf16(a0l, b1h, acc[0][1], 0, 0, 0);
      acc[1][0] = __builtin_amdgcn_mfma_f32_16x16x32_bf16(a1l, b0h, acc[1][0], 0, 0, 0);
      acc[1][1] = __builtin_amdgcn_mfma_f32_16x16x32_bf16(a1l, b1h, acc[1][1], 0, 0, 0);
    }
    __syncthreads();
  }

#pragma unroll
  for (int rb = 0; rb < 2; rb++)
#pragma unroll
    for (int cb = 0; cb < 2; cb++){
      const int col = qc + cb*16 + (lane & 15);
#pragma unroll
      for (int r = 0; r < 4; r++){
        const int row = mbase + qr + rb*16 + (lane >> 4)*4 + r;
        if (row < r1)
          qp[((long long)kb * Bsz + row) * Aact + col] = acc[rb][cb][r];
      }
    }
}

// ---------------- per-row action head: q = sum(qp) + abo[o], softmax, argmax (1 wave/row) ----------
__global__ __launch_bounds__(64)
void act_kernel(const float* __restrict__ qp, const float* __restrict__ abo,
                const int* __restrict__ order, const int* __restrict__ offsets,
                float* __restrict__ out)
{
  const int r = blockIdx.x;
  int o = 0;
#pragma unroll
  for (int i = 1; i < 8; ++i) if (offsets[i] <= r) o = i;
  const int a = threadIdx.x;
  const long long idx = (long long)r * Aact + a;
  float q = qp[idx] + qp[(long long)Bsz*Aact + idx] + qp[2ll*Bsz*Aact + idx]
          + qp[3ll*Bsz*Aact + idx] + abo[o * Aact + a];
  float m = q;
#pragma unroll
  for (int off = 32; off; off >>= 1) m = fmaxf(m, __shfl_xor(m, off));
  float e = expf(q - m);
  float s = e;
#pragma unroll
  for (int off = 32; off; off >>= 1) s += __shfl_xor(s, off);
  const int b = order[r];
  out[OFF_ACT + b * Aact + a] = e / s;
  unsigned long long msk = __ballot(q == m);
  if (a == 0) out[OFF_SACT + b] = (float)__builtin_ctzll(msk);
}

// ---------------- per-row head: opt logits + softmax + argmax + gumbel sel + termination ----------------
__global__ __launch_bounds__(256)
void head_kernel(const float* __restrict__ h1, const float* __restrict__ th,
                 const float* __restrict__ ow2, const float* __restrict__ ob2,
                 const float* __restrict__ tw2, const float* __restrict__ tb2,
                 float* __restrict__ out, int* __restrict__ sel)
{
  const int b = blockIdx.x;
  const int t = threadIdx.x;
  const float* hrow = h1 + b * Hdim;
  const float* trow = th + b * Hdim;

  float acc[8] = {}; float accT = 0.f;
  for (int k = t; k < Hdim; k += 256){
    float hv = hrow[k];
    const float* w = ow2 + k * 8;
#pragma unroll
    for (int o2 = 0; o2 < 8; ++o2) acc[o2] += hv * w[o2];
    accT += trow[k] * tw2[k];
  }
#pragma unroll
  for (int o2 = 0; o2 < 8; ++o2)
    for (int off = 32; off; off >>= 1) acc[o2] += __shfl_down(acc[o2], off);
  for (int off = 32; off; off >>= 1) accT += __shfl_down(accT, off);

  __shared__ float wred[4][9];
  __shared__ float logits[8];
  __shared__ float gum[8];
  const int wave = t >> 6, lane = t & 63;
  if (lane == 0){
#pragma unroll
    for (int o2 = 0; o2 < 8; ++o2) wred[wave][o2] = acc[o2];
    wred[wave][8] = accT;
  }
  __syncthreads();
  if (t < 9){
    float s = wred[0][t] + wred[1][t] + wred[2][t] + wred[3][t];
    if (t < 8) logits[t] = s + ob2[t];
    else       out[OFF_TERM + b] = 1.f / (1.f + expf(-(s + tb2[0])));
  }
  __syncthreads();
  if (t < 8) gum[t] = logits[t] + gumbel_at(b * 8 + t);
  __syncthreads();
  if (t == 0){
    float m = logits[0]; int am = 0;
#pragma unroll
    for (int o2 = 1; o2 < 8; ++o2) if (logits[o2] > m){ m = logits[o2]; am = o2; }
    float p[8]; float s = 0.f;
#pragma unroll
    for (int o2 = 0; o2 < 8; ++o2){ p[o2] = expf(logits[o2] - m); s += p[o2]; }
    float inv = 1.f / s;
#pragma unroll
    for (int o2 = 0; o2 < 8; ++o2) out[b * 8 + o2] = p[o2] * inv;
    out[OFF_OARG + b] = (float)am;
    float gm = gum[0]; int gs = 0;
#pragma unroll
    for (int o2 = 1; o2 < 8; ++o2) if (gum[o2] > gm){ gm = gum[o2]; gs = o2; }
    sel[b] = gs;
  }
}

// ---------------- routing: bucket samples by expert + emit row-tile list ----------------
__global__ void route_kernel(const int* __restrict__ sel, int* __restrict__ order,
                             int* __restrict__ offsets, int* __restrict__ tlist)
{
  __shared__ int cnt[8];
  __shared__ int base[8];
  const int t = threadIdx.x;
  if (t < 8) cnt[t] = 0;
  __syncthreads();
  const int s = sel[t];
  atomicAdd(&cnt[s], 1);
  __syncthreads();
  if (t == 0){
    int a = 0;
    for (int o = 0; o < 8; ++o){ offsets[o] = a; base[o] = a; a += cnt[o]; }
    offsets[8] = a;
    int nt = 0;
    for (int o = 0; o < 8; ++o)
      for (int mb = offsets[o]; mb < offsets[o] + cnt[o]; mb += 64){
        tlist[1 + 2*nt] = o; tlist[2 + 2*nt] = mb; ++nt;
      }
    tlist[0] = nt;
  }
  __syncthreads();
  const int pos = atomicAdd(&base[s], 1);
  order[pos] = t;   // permutation within an expert is nondeterministic; outputs don't depend on it
}

extern "C" void kernel_launch(void* const* d_in, const int* in_sizes, int n_in,
                              void* d_out, int out_size, void* d_ws, size_t ws_size,
                              hipStream_t stream)
{
  (void)in_sizes; (void)n_in; (void)out_size; (void)ws_size;
  const float* state = (const float*)d_in[0];
  const float* ow1   = (const float*)d_in[1];
  const float* ob1   = (const float*)d_in[2];
  const float* ow2   = (const float*)d_in[3];
  const float* ob2   = (const float*)d_in[4];
  const float* aw1   = (const float*)d_in[5];
  const float* ab1   = (const float*)d_in[6];
  const float* awh   = (const float*)d_in[7];
  const float* abh   = (const float*)d_in[8];
  const float* awo   = (const float*)d_in[9];
  const float* abo   = (const float*)d_in[10];
  const float* tw1   = (const float*)d_in[11];
  const float* tb1   = (const float*)d_in[12];
  const float* tw2   = (const float*)d_in[13];
  const float* tb2   = (const float*)d_in[14];
  float* out = (float*)d_out;

  float* h1 = (float*)d_ws;                                 // dense opt hidden (fp32)
  float* h2 = h1 + (long long)Bsz * Hdim;                   // dense term hidden (fp32)
  float* qp = h2 + (long long)Bsz * Hdim;                   // q partials [4][1024][64]
  unsigned short* h1hi = (unsigned short*)(qp + 4ll * Bsz * Aact);  // L1 out hi/lo [1024][1024]
  unsigned short* h1lo = h1hi + (long long)Bsz * Hdim;
  unsigned short* h2hi = h1lo + (long long)Bsz * Hdim;      // L2 out hi/lo [1024][1024]
  unsigned short* h2lo = h2hi + (long long)Bsz * Hdim;
  int* sel     = (int*)(h2lo + (long long)Bsz * Hdim);
  int* order   = sel + Bsz;
  int* offsets = order + Bsz;
  int* tlist   = offsets + 9;           // [ntiles | (expert,mbase) * MAXT]

  // 1. dense pair (A = fp32 state, split in staging): h1 = relu(st@ow1+ob1), h2 = relu(st@tw1+tb1)
  mfma_gemm<true, false, false, true><<<dim3(16, 16, 2), 256, 0, stream>>>(
      nullptr, nullptr, state, Din, ow1, tw1, 0, ob1, tb1, 0, h1, h2, nullptr, nullptr,
      Hdim, Din, nullptr, nullptr, nullptr);
  // 2. heads: opt softmax/argmax, gumbel categorical sel, termination sigmoid
  head_kernel<<<dim3(Bsz), 256, 0, stream>>>(h1, h2, ow2, ob2, tw2, tb2, out, sel);
  // 3. bucket samples by expert + tile list
  route_kernel<<<dim3(1), 1024, 0, stream>>>(sel, order, offsets, tlist);
  // 4. expert L1 (A = fp32 state rows gathered, split in staging):
  //    h1hi/lo[r] = split(relu(state[order[r]] @ aw1[o] + ab1[o]))
  mfma_gemm<false, true, true, true><<<dim3(MAXT, 16), 256, 0, stream>>>(
      nullptr, nullptr, state, Din, aw1, nullptr, (long long)Din*Hdim, ab1, nullptr, Hdim,
      nullptr, nullptr, h1hi, h1lo, Hdim, Din, order, offsets, tlist);
  // 5. expert L2 (A = pre-split h1): h2hi/lo[r] = split(relu(h1[r] @ awh[o,0] + abh[o,0]))
  mfma_gemm<false, false, true, false><<<dim3(MAXT, 16), 256, 0, stream>>>(
      h1hi, h1lo, nullptr, Hdim, awh, nullptr, (long long)Hdim*Hdim, abh, nullptr, Hdim,
      nullptr, nullptr, h2hi, h2lo, Hdim, Hdim, nullptr, offsets, tlist);
  // 6. q partials: qp[kb] = h2 @ awo[o] (chunk kb of K)   [MFMA, split-K x4]
  q_mfma<<<dim3(MAXT, 4), 256, 0, stream>>>(h2hi, h2lo, awo, qp, offsets, tlist);
  // 7. action head: q = sum(qp)+abo, softmax, argmax
  act_kernel<<<dim3(Bsz), 64, 0, stream>>>(qp, abo, order, offsets, out);
}